// Round 1
// baseline (2399.945 us; speedup 1.0000x reference)
//
#include <hip/hip_runtime.h>

#define N_NODES 32000
#define NPG     2000
#define NGRAPH  16
#define K_ASSIGN 1600
#define KPG     100
#define D_FEAT  128
#define N_EDGES 512000

__device__ __forceinline__ float frelu(float v) { return fmaxf(v, 0.0f); }

__device__ __forceinline__ unsigned short f2bf(float f) {
  unsigned u = __float_as_uint(f);
  u += 0x7FFFu + ((u >> 16) & 1u);
  return (unsigned short)(u >> 16);
}
__device__ __forceinline__ float bf2f(unsigned short s) {
  return __uint_as_float(((unsigned)s) << 16);
}

// ---------------------------------------------------------------------------
// Edge scatter for GIN aggregation: agg[dst] += h[src]; deg[dst] += 1
// 8 edges per 256-thread block, 32 lanes/edge, float4 per lane.
// ---------------------------------------------------------------------------
__global__ __launch_bounds__(256) void gin_edge(
    const int* __restrict__ src, const int* __restrict__ dst,
    const float* __restrict__ h, float* __restrict__ agg,
    float* __restrict__ deg) {
  int e = blockIdx.x * 8 + (threadIdx.x >> 5);
  int lane = threadIdx.x & 31;
  int s = src[e], d = dst[e];
  float4 hv = *(const float4*)(h + (size_t)s * 128 + lane * 4);
  float* ap = agg + (size_t)d * 128 + lane * 4;
  atomicAdd(ap + 0, hv.x);
  atomicAdd(ap + 1, hv.y);
  atomicAdd(ap + 2, hv.z);
  atomicAdd(ap + 3, hv.w);
  if (lane == 0) atomicAdd(deg + d, 1.0f);
}

// ---------------------------------------------------------------------------
// x = h + agg / max(deg, 1)
// ---------------------------------------------------------------------------
__global__ __launch_bounds__(256) void compute_x(
    const float* __restrict__ h, const float* __restrict__ agg,
    const float* __restrict__ deg, float* __restrict__ x) {
  int i = blockIdx.x * 256 + threadIdx.x;  // float4 index, total N*128/4
  int n = i >> 5;
  float inv = 1.0f / fmaxf(deg[n], 1.0f);
  float4 hv = ((const float4*)h)[i];
  float4 av = ((const float4*)agg)[i];
  float4 o;
  o.x = hv.x + av.x * inv;
  o.y = hv.y + av.y * inv;
  o.z = hv.z + av.z * inv;
  o.w = hv.w + av.w * inv;
  ((float4*)x)[i] = o;
}

// ---------------------------------------------------------------------------
// C = relu(A @ W + bias), A [N x 128], W [128 x 128].
// 64-row tile per block; thread = 8 rows x 4 cols.
// ---------------------------------------------------------------------------
__global__ __launch_bounds__(256) void gemm_d128(
    const float* __restrict__ A, const float* __restrict__ W,
    const float* __restrict__ bias, float* __restrict__ C) {
  __shared__ float xs[64][129];
  int t = threadIdx.x;
  size_t base = (size_t)blockIdx.x * 64 * 128;
#pragma unroll
  for (int i = 0; i < 8; i++) {
    int fi = t + i * 256;
    int r = fi >> 5, c4 = (fi & 31) << 2;
    float4 v = *(const float4*)(A + base + (size_t)r * 128 + c4);
    xs[r][c4] = v.x; xs[r][c4 + 1] = v.y; xs[r][c4 + 2] = v.z; xs[r][c4 + 3] = v.w;
  }
  __syncthreads();
  int cg = (t & 31) << 2;
  int rg = (t >> 5) << 3;
  float acc[8][4] = {};
  for (int k = 0; k < 128; k++) {
    float4 w = *(const float4*)(W + (size_t)k * 128 + cg);
#pragma unroll
    for (int i = 0; i < 8; i++) {
      float aV = xs[rg + i][k];
      acc[i][0] += aV * w.x; acc[i][1] += aV * w.y;
      acc[i][2] += aV * w.z; acc[i][3] += aV * w.w;
    }
  }
  float4 bv = *(const float4*)(bias + cg);
#pragma unroll
  for (int i = 0; i < 8; i++) {
    float4 o;
    o.x = frelu(acc[i][0] + bv.x);
    o.y = frelu(acc[i][1] + bv.y);
    o.z = frelu(acc[i][2] + bv.z);
    o.w = frelu(acc[i][3] + bv.w);
    *(float4*)(C + base + (size_t)(rg + i) * 128 + cg) = o;
  }
}

// ---------------------------------------------------------------------------
// Fused assign path. Per block: 64 rows of one graph.
// Phase 1: xs[64][64] = relu(x_tile @ W1p[:, k0:k0+64] + b1p)  (x1p slice)
// Phase 2: acc += xs @ W2p[k0:k0+64, g*100:(g+1)*100]
// Only the 100 in-graph columns are ever computed (mask kills the rest).
// ---------------------------------------------------------------------------
__global__ __launch_bounds__(256) void fused_assign(
    const float* __restrict__ x, const float* __restrict__ W1p,
    const float* __restrict__ b1p, const float* __restrict__ W2p,
    const float* __restrict__ b2p, float* __restrict__ assign_out) {
  __shared__ float xt[64][129];            // 33,024 B
  __shared__ float xs[64][65];             // 16,640 B
  __shared__ unsigned short ws[64][100];   // 12,800 B  (bf16 W2p slice)
  int bid = blockIdx.x;
  int g = bid >> 5, rb = bid & 31;
  int row0 = rb * 64;
  int n0 = g * NPG + row0;
  int t = threadIdx.x;

  // stage x tile (zero-fill rows past NPG)
#pragma unroll
  for (int i = 0; i < 8; i++) {
    int fi = t + i * 256;
    int r = fi >> 5, c4 = (fi & 31) << 2;
    float4 v = make_float4(0.f, 0.f, 0.f, 0.f);
    if (row0 + r < NPG) v = *(const float4*)(x + (size_t)(n0 + r) * 128 + c4);
    xt[r][c4] = v.x; xt[r][c4 + 1] = v.y; xt[r][c4 + 2] = v.z; xt[r][c4 + 3] = v.w;
  }
  __syncthreads();

  int rg2 = (t >> 5) << 3;   // phase-2: 8 rows
  int cg2 = t & 31;          // phase-2: cols cg2 + 32j
  int rg1 = (t >> 4) << 2;   // phase-1: 4 rows
  int kk1 = (t & 15) << 2;   // phase-1: 4 kk cols
  float acc[8][4] = {};

  for (int k0 = 0; k0 < K_ASSIGN; k0 += 64) {
    // ---- phase 1: compute x1p slice into registers ----
    float p[4][4] = {};
    for (int j = 0; j < 128; j++) {
      float4 w = *(const float4*)(W1p + (size_t)j * K_ASSIGN + k0 + kk1);
#pragma unroll
      for (int i = 0; i < 4; i++) {
        float aV = xt[rg1 + i][j];
        p[i][0] += aV * w.x; p[i][1] += aV * w.y;
        p[i][2] += aV * w.z; p[i][3] += aV * w.w;
      }
    }
    float4 b1 = *(const float4*)(b1p + k0 + kk1);
    __syncthreads();  // previous phase-2 done reading xs/ws
#pragma unroll
    for (int i = 0; i < 4; i++) {
      xs[rg1 + i][kk1 + 0] = frelu(p[i][0] + b1.x);
      xs[rg1 + i][kk1 + 1] = frelu(p[i][1] + b1.y);
      xs[rg1 + i][kk1 + 2] = frelu(p[i][2] + b1.z);
      xs[rg1 + i][kk1 + 3] = frelu(p[i][3] + b1.w);
    }
    // ---- stage W2p slice (64 x 100) as bf16 ----
#pragma unroll
    for (int i = 0; i < 25; i++) {
      int idx = t + i * 256;  // exactly 6400
      int kk = idx / 100, c = idx % 100;
      ws[kk][c] = f2bf(W2p[(size_t)(k0 + kk) * K_ASSIGN + g * KPG + c]);
    }
    __syncthreads();
    // ---- phase 2: acc += xs @ ws ----
    for (int kk = 0; kk < 64; kk++) {
      float w0 = bf2f(ws[kk][cg2]);
      float w1 = bf2f(ws[kk][cg2 + 32]);
      float w2 = bf2f(ws[kk][cg2 + 64]);
      float w3 = (cg2 < 4) ? bf2f(ws[kk][cg2 + 96]) : 0.0f;
#pragma unroll
      for (int i = 0; i < 8; i++) {
        float aV = xs[rg2 + i][kk];
        acc[i][0] += aV * w0; acc[i][1] += aV * w1;
        acc[i][2] += aV * w2; acc[i][3] += aV * w3;
      }
    }
  }

  // epilogue: bias + relu, store active-100 columns
  for (int i = 0; i < 8; i++) {
    int rl = row0 + rg2 + i;
    if (rl < NPG) {
      size_t n = (size_t)g * NPG + rl;
#pragma unroll
      for (int j = 0; j < 4; j++) {
        int c = cg2 + 32 * j;
        if (c < KPG)
          assign_out[n * KPG + c] = frelu(acc[i][j] + b2p[g * KPG + c]);
      }
    }
  }
}

// ---------------------------------------------------------------------------
// Masked softmax over the 100 active cols, replicating the reference exactly:
// softmax over full K (masked entries = 0) then mask + renormalize.
// One wave per node.
// ---------------------------------------------------------------------------
__global__ __launch_bounds__(256) void softmax100(float* __restrict__ assign) {
  int n = blockIdx.x * 4 + (threadIdx.x >> 6);
  int lane = threadIdx.x & 63;
  float* row = assign + (size_t)n * KPG;
  float v1 = row[lane];
  bool has2 = lane < (KPG - 64);
  float v2 = has2 ? row[64 + lane] : 0.0f;
  float m = fmaxf(fmaxf(v1, v2), 0.0f);  // full-K max includes the zeros
#pragma unroll
  for (int o = 32; o > 0; o >>= 1) m = fmaxf(m, __shfl_xor(m, o));
  float e1 = expf(v1 - m);
  float e2 = has2 ? expf(v2 - m) : 0.0f;
  float s = e1 + e2;
#pragma unroll
  for (int o = 32; o > 0; o >>= 1) s += __shfl_xor(s, o);
  float denom = s + (float)(K_ASSIGN - KPG) * expf(-m);  // masked zeros' exp
  // out = (e/denom) / (s/denom + 1e-13) = e / (s + 1e-13*denom)
  float scale = 1.0f / (s + 1e-13f * denom);
  row[lane] = e1 * scale;
  if (has2) row[64 + lane] = e2 * scale;
}

// ---------------------------------------------------------------------------
// tmp[dst] += assign[src]  (100-wide rows; 8 edges/block, 25 of 32 lanes)
// ---------------------------------------------------------------------------
__global__ __launch_bounds__(256) void tmp_edge(
    const int* __restrict__ src, const int* __restrict__ dst,
    const float* __restrict__ assign, float* __restrict__ tmp) {
  int e = blockIdx.x * 8 + (threadIdx.x >> 5);
  int lane = threadIdx.x & 31;
  if (lane >= 25) return;
  int s = src[e], d = dst[e];
  float4 av = *(const float4*)(assign + (size_t)s * KPG + lane * 4);
  float* tp = tmp + (size_t)d * KPG + lane * 4;
  atomicAdd(tp + 0, av.x);
  atomicAdd(tp + 1, av.y);
  atomicAdd(tp + 2, av.z);
  atomicAdd(tp + 3, av.w);
}

// ---------------------------------------------------------------------------
// h_pool[g*100+k1][d] = sum_n assign[n][k1] * feat[n][d]  per graph.
// 16 chunks of 125 rows per graph; atomicAdd partials.
// ---------------------------------------------------------------------------
__global__ __launch_bounds__(256) void pool_gemm(
    const float* __restrict__ assign, const float* __restrict__ feat,
    float* __restrict__ out_hpool) {
  __shared__ float as[25][101];
  __shared__ float fs[25][129];
  int g = blockIdx.x >> 4, ch = blockIdx.x & 15;
  int nbase0 = g * NPG + ch * 125;
  int t = threadIdx.x;
  int a = t >> 4, b = t & 15;
  float acc[7][8] = {};
  for (int tile = 0; tile < 5; tile++) {
    int nb = nbase0 + tile * 25;
    __syncthreads();
    for (int i = 0; i < 10; i++) {
      int idx = t + i * 256;
      if (idx < 2500) {
        int r = idx / 100, c = idx % 100;
        as[r][c] = assign[(size_t)(nb + r) * KPG + c];
      }
    }
    for (int i = 0; i < 13; i++) {
      int idx = t + i * 256;
      if (idx < 3200) {
        int r = idx >> 7, c = idx & 127;
        fs[r][c] = feat[(size_t)(nb + r) * 128 + c];
      }
    }
    __syncthreads();
    for (int n = 0; n < 25; n++) {
      float av[7], fv[8];
#pragma unroll
      for (int i = 0; i < 7; i++) {
        int k1 = a + 16 * i;
        av[i] = (k1 < KPG) ? as[n][k1] : 0.0f;
      }
#pragma unroll
      for (int j = 0; j < 8; j++) fv[j] = fs[n][b + 16 * j];
#pragma unroll
      for (int i = 0; i < 7; i++)
#pragma unroll
        for (int j = 0; j < 8; j++) acc[i][j] += av[i] * fv[j];
    }
  }
  for (int i = 0; i < 7; i++) {
    int k1 = a + 16 * i;
    if (k1 < KPG)
      for (int j = 0; j < 8; j++)
        atomicAdd(out_hpool + (size_t)(g * KPG + k1) * 128 + b + 16 * j,
                  acc[i][j]);
  }
}

// ---------------------------------------------------------------------------
// adj block-diagonal: adj[g*100+k1][g*100+k2] = sum_n assign[n][k1]*tmp[n][k2]
// ---------------------------------------------------------------------------
__global__ __launch_bounds__(256) void adj_gemm(
    const float* __restrict__ assign, const float* __restrict__ tmp,
    float* __restrict__ out_adj) {
  __shared__ float as[25][101];
  __shared__ float ts[25][101];
  int g = blockIdx.x >> 4, ch = blockIdx.x & 15;
  int nbase0 = g * NPG + ch * 125;
  int t = threadIdx.x;
  int a = t >> 4, b = t & 15;
  float acc[7][7] = {};
  for (int tile = 0; tile < 5; tile++) {
    int nb = nbase0 + tile * 25;
    __syncthreads();
    for (int i = 0; i < 10; i++) {
      int idx = t + i * 256;
      if (idx < 2500) {
        int r = idx / 100, c = idx % 100;
        as[r][c] = assign[(size_t)(nb + r) * KPG + c];
        ts[r][c] = tmp[(size_t)(nb + r) * KPG + c];
      }
    }
    __syncthreads();
    for (int n = 0; n < 25; n++) {
      float av[7], tv[7];
#pragma unroll
      for (int i = 0; i < 7; i++) {
        int k1 = a + 16 * i;
        av[i] = (k1 < KPG) ? as[n][k1] : 0.0f;
      }
#pragma unroll
      for (int j = 0; j < 7; j++) {
        int k2 = b + 16 * j;
        tv[j] = (k2 < KPG) ? ts[n][k2] : 0.0f;
      }
#pragma unroll
      for (int i = 0; i < 7; i++)
#pragma unroll
        for (int j = 0; j < 7; j++) acc[i][j] += av[i] * tv[j];
    }
  }
  for (int i = 0; i < 7; i++) {
    int k1 = a + 16 * i;
    if (k1 >= KPG) continue;
    for (int j = 0; j < 7; j++) {
      int k2 = b + 16 * j;
      if (k2 < KPG)
        atomicAdd(out_adj + (size_t)(g * KPG + k1) * K_ASSIGN + g * KPG + k2,
                  acc[i][j]);
    }
  }
}

extern "C" void kernel_launch(void* const* d_in, const int* in_sizes, int n_in,
                              void* d_out, int out_size, void* d_ws,
                              size_t ws_size, hipStream_t stream) {
  (void)in_sizes; (void)n_in; (void)ws_size;
  const float* h   = (const float*)d_in[0];
  const int*   src = (const int*)d_in[1];
  const int*   dst = (const int*)d_in[2];
  const float* W1f = (const float*)d_in[3];
  const float* b1f = (const float*)d_in[4];
  const float* W2f = (const float*)d_in[5];
  const float* b2f = (const float*)d_in[6];
  const float* W1p = (const float*)d_in[7];
  const float* b1p = (const float*)d_in[8];
  const float* W2p = (const float*)d_in[9];
  const float* b2p = (const float*)d_in[10];

  float* out_adj   = (float*)d_out;
  float* out_hpool = out_adj + (size_t)K_ASSIGN * K_ASSIGN;

  char* ws = (char*)d_ws;
  float* agg    = (float*)(ws + 0);           // 16,384,000 B
  float* deg    = (float*)(ws + 16384000);    //    128,000 B
  float* x      = (float*)(ws + 16512000);    // 16,384,000 B
  float* x1f    = (float*)(ws + 32896000);    // 16,384,000 B
  float* feat   = (float*)(ws + 49280000);    // 16,384,000 B
  float* assign = (float*)(ws + 65664000);    // 12,800,000 B
  float* tmp    = (float*)(ws + 78464000);    // 12,800,000 B  (total ~91.3 MB)

  hipMemsetAsync(agg, 0, 16512000, stream);                    // agg + deg
  hipMemsetAsync(tmp, 0, 12800000, stream);
  hipMemsetAsync(d_out, 0, (size_t)out_size * sizeof(float), stream);

  gin_edge<<<N_EDGES / 8, 256, 0, stream>>>(src, dst, h, agg, deg);
  compute_x<<<(N_NODES * 128 / 4) / 256, 256, 0, stream>>>(h, agg, deg, x);
  gemm_d128<<<N_NODES / 64, 256, 0, stream>>>(x, W1f, b1f, x1f);
  gemm_d128<<<N_NODES / 64, 256, 0, stream>>>(x1f, W2f, b2f, feat);
  fused_assign<<<512, 256, 0, stream>>>(x, W1p, b1p, W2p, b2p, assign);
  softmax100<<<N_NODES / 4, 256, 0, stream>>>(assign);
  tmp_edge<<<N_EDGES / 8, 256, 0, stream>>>(src, dst, assign, tmp);
  pool_gemm<<<NGRAPH * 16, 256, 0, stream>>>(assign, feat, out_hpool);
  adj_gemm<<<NGRAPH * 16, 256, 0, stream>>>(assign, tmp, out_adj);
}

// Round 2
// 832.599 us; speedup vs baseline: 2.8825x; 2.8825x over previous
//
#include <hip/hip_runtime.h>

#define N_NODES 32000
#define NPG     2000
#define NGRAPH  16
#define K_ASSIGN 1600
#define KPG     100
#define D_FEAT  128
#define N_EDGES 512000

__device__ __forceinline__ float frelu(float v) { return fmaxf(v, 0.0f); }

__device__ __forceinline__ unsigned short f2bf(float f) {
  unsigned u = __float_as_uint(f);
  u += 0x7FFFu + ((u >> 16) & 1u);
  return (unsigned short)(u >> 16);
}
__device__ __forceinline__ float bf2f(unsigned short s) {
  return __uint_as_float(((unsigned)s) << 16);
}

// ---------------------------------------------------------------------------
// CSR build: histogram of dst
// ---------------------------------------------------------------------------
__global__ __launch_bounds__(256) void edge_hist(
    const int* __restrict__ dst, int* __restrict__ cnt) {
  int e = blockIdx.x * 256 + threadIdx.x;
  if (e < N_EDGES) atomicAdd(&cnt[dst[e]], 1);
}

// exclusive prefix scan of 32000 counts -> rowstart[32001]; 1 block x 256 thr
__global__ __launch_bounds__(256) void scan_counts(
    const int* __restrict__ cnt, int* __restrict__ rowstart) {
  __shared__ int sums[256];
  int t = threadIdx.x;
  int base = t * 125;
  int s = 0;
  for (int i = 0; i < 125; i++) s += cnt[base + i];
  sums[t] = s;
  __syncthreads();
  for (int off = 1; off < 256; off <<= 1) {
    int v = (t >= off) ? sums[t - off] : 0;
    __syncthreads();
    sums[t] += v;
    __syncthreads();
  }
  int run = (t == 0) ? 0 : sums[t - 1];
  for (int i = 0; i < 125; i++) {
    rowstart[base + i] = run;
    run += cnt[base + i];
  }
  if (t == 255) rowstart[32000] = run;
}

// fill bucket: src indices grouped by dst
__global__ __launch_bounds__(256) void edge_fill(
    const int* __restrict__ src, const int* __restrict__ dst,
    const int* __restrict__ rowstart, int* __restrict__ cursor,
    int* __restrict__ bucket) {
  int e = blockIdx.x * 256 + threadIdx.x;
  if (e < N_EDGES) {
    int d = dst[e];
    int pos = atomicAdd(&cursor[d], 1);
    bucket[rowstart[d] + pos] = src[e];
  }
}

// ---------------------------------------------------------------------------
// Gather aggregation + compute_x fused: x[n] = h[n] + mean_{e->n} h[src_e]
// One wave per node, lane = 2 feature dims (float2).
// ---------------------------------------------------------------------------
__global__ __launch_bounds__(256) void gin_gather(
    const int* __restrict__ rowstart, const int* __restrict__ bucket,
    const float* __restrict__ h, float* __restrict__ x) {
  int n = blockIdx.x * 4 + (threadIdx.x >> 6);
  int lane = threadIdx.x & 63;
  int rs = rowstart[n], re = rowstart[n + 1];
  const float2* h2 = (const float2*)h;
  float2 acc = make_float2(0.f, 0.f);
  int e = rs;
  for (; e + 4 <= re; e += 4) {
    int s0 = bucket[e], s1 = bucket[e + 1], s2 = bucket[e + 2], s3 = bucket[e + 3];
    float2 a0 = h2[(size_t)s0 * 64 + lane];
    float2 a1 = h2[(size_t)s1 * 64 + lane];
    float2 a2 = h2[(size_t)s2 * 64 + lane];
    float2 a3 = h2[(size_t)s3 * 64 + lane];
    acc.x += (a0.x + a1.x) + (a2.x + a3.x);
    acc.y += (a0.y + a1.y) + (a2.y + a3.y);
  }
  for (; e < re; e++) {
    int s0 = bucket[e];
    float2 a0 = h2[(size_t)s0 * 64 + lane];
    acc.x += a0.x;
    acc.y += a0.y;
  }
  float invd = 1.0f / fmaxf((float)(re - rs), 1.0f);
  float2 hv = h2[(size_t)n * 64 + lane];
  float2 o;
  o.x = hv.x + acc.x * invd;
  o.y = hv.y + acc.y * invd;
  ((float2*)x)[(size_t)n * 64 + lane] = o;
}

// ---------------------------------------------------------------------------
// tmp[n] = sum_{e->n} assign[src_e]  (100-wide). One wave/node, 50 lanes.
// ---------------------------------------------------------------------------
__global__ __launch_bounds__(256) void tmp_gather(
    const int* __restrict__ rowstart, const int* __restrict__ bucket,
    const float* __restrict__ assign, float* __restrict__ tmp) {
  int n = blockIdx.x * 4 + (threadIdx.x >> 6);
  int lane = threadIdx.x & 63;
  if (lane >= 50) return;
  int rs = rowstart[n], re = rowstart[n + 1];
  float2 acc = make_float2(0.f, 0.f);
  int e = rs;
  for (; e + 2 <= re; e += 2) {
    int s0 = bucket[e], s1 = bucket[e + 1];
    float2 a0 = *(const float2*)(assign + (size_t)s0 * KPG + lane * 2);
    float2 a1 = *(const float2*)(assign + (size_t)s1 * KPG + lane * 2);
    acc.x += a0.x + a1.x;
    acc.y += a0.y + a1.y;
  }
  for (; e < re; e++) {
    int s0 = bucket[e];
    float2 a0 = *(const float2*)(assign + (size_t)s0 * KPG + lane * 2);
    acc.x += a0.x;
    acc.y += a0.y;
  }
  *(float2*)(tmp + (size_t)n * KPG + lane * 2) = acc;
}

// ---------------------------------------------------------------------------
// C = relu(A @ W + bias), A [N x 128], W [128 x 128].
// ---------------------------------------------------------------------------
__global__ __launch_bounds__(256) void gemm_d128(
    const float* __restrict__ A, const float* __restrict__ W,
    const float* __restrict__ bias, float* __restrict__ C) {
  __shared__ float xs[64][129];
  int t = threadIdx.x;
  size_t base = (size_t)blockIdx.x * 64 * 128;
#pragma unroll
  for (int i = 0; i < 8; i++) {
    int fi = t + i * 256;
    int r = fi >> 5, c4 = (fi & 31) << 2;
    float4 v = *(const float4*)(A + base + (size_t)r * 128 + c4);
    xs[r][c4] = v.x; xs[r][c4 + 1] = v.y; xs[r][c4 + 2] = v.z; xs[r][c4 + 3] = v.w;
  }
  __syncthreads();
  int cg = (t & 31) << 2;
  int rg = (t >> 5) << 3;
  float acc[8][4] = {};
  for (int k = 0; k < 128; k++) {
    float4 w = *(const float4*)(W + (size_t)k * 128 + cg);
#pragma unroll
    for (int i = 0; i < 8; i++) {
      float aV = xs[rg + i][k];
      acc[i][0] += aV * w.x; acc[i][1] += aV * w.y;
      acc[i][2] += aV * w.z; acc[i][3] += aV * w.w;
    }
  }
  float4 bv = *(const float4*)(bias + cg);
#pragma unroll
  for (int i = 0; i < 8; i++) {
    float4 o;
    o.x = frelu(acc[i][0] + bv.x);
    o.y = frelu(acc[i][1] + bv.y);
    o.z = frelu(acc[i][2] + bv.z);
    o.w = frelu(acc[i][3] + bv.w);
    *(float4*)(C + base + (size_t)(rg + i) * 128 + cg) = o;
  }
}

// ---------------------------------------------------------------------------
// Fused assign path (see round-0 comments). Only 100 in-graph cols computed.
// ---------------------------------------------------------------------------
__global__ __launch_bounds__(256) void fused_assign(
    const float* __restrict__ x, const float* __restrict__ W1p,
    const float* __restrict__ b1p, const float* __restrict__ W2p,
    const float* __restrict__ b2p, float* __restrict__ assign_out) {
  __shared__ float xt[64][129];
  __shared__ float xs[64][65];
  __shared__ unsigned short ws[64][100];
  int bid = blockIdx.x;
  int g = bid >> 5, rb = bid & 31;
  int row0 = rb * 64;
  int n0 = g * NPG + row0;
  int t = threadIdx.x;

#pragma unroll
  for (int i = 0; i < 8; i++) {
    int fi = t + i * 256;
    int r = fi >> 5, c4 = (fi & 31) << 2;
    float4 v = make_float4(0.f, 0.f, 0.f, 0.f);
    if (row0 + r < NPG) v = *(const float4*)(x + (size_t)(n0 + r) * 128 + c4);
    xt[r][c4] = v.x; xt[r][c4 + 1] = v.y; xt[r][c4 + 2] = v.z; xt[r][c4 + 3] = v.w;
  }
  __syncthreads();

  int rg2 = (t >> 5) << 3;
  int cg2 = t & 31;
  int rg1 = (t >> 4) << 2;
  int kk1 = (t & 15) << 2;
  float acc[8][4] = {};

  for (int k0 = 0; k0 < K_ASSIGN; k0 += 64) {
    float p[4][4] = {};
    for (int j = 0; j < 128; j++) {
      float4 w = *(const float4*)(W1p + (size_t)j * K_ASSIGN + k0 + kk1);
#pragma unroll
      for (int i = 0; i < 4; i++) {
        float aV = xt[rg1 + i][j];
        p[i][0] += aV * w.x; p[i][1] += aV * w.y;
        p[i][2] += aV * w.z; p[i][3] += aV * w.w;
      }
    }
    float4 b1 = *(const float4*)(b1p + k0 + kk1);
    __syncthreads();
#pragma unroll
    for (int i = 0; i < 4; i++) {
      xs[rg1 + i][kk1 + 0] = frelu(p[i][0] + b1.x);
      xs[rg1 + i][kk1 + 1] = frelu(p[i][1] + b1.y);
      xs[rg1 + i][kk1 + 2] = frelu(p[i][2] + b1.z);
      xs[rg1 + i][kk1 + 3] = frelu(p[i][3] + b1.w);
    }
#pragma unroll
    for (int i = 0; i < 25; i++) {
      int idx = t + i * 256;
      int kk = idx / 100, c = idx % 100;
      ws[kk][c] = f2bf(W2p[(size_t)(k0 + kk) * K_ASSIGN + g * KPG + c]);
    }
    __syncthreads();
    for (int kk = 0; kk < 64; kk++) {
      float w0 = bf2f(ws[kk][cg2]);
      float w1 = bf2f(ws[kk][cg2 + 32]);
      float w2 = bf2f(ws[kk][cg2 + 64]);
      float w3 = (cg2 < 4) ? bf2f(ws[kk][cg2 + 96]) : 0.0f;
#pragma unroll
      for (int i = 0; i < 8; i++) {
        float aV = xs[rg2 + i][kk];
        acc[i][0] += aV * w0; acc[i][1] += aV * w1;
        acc[i][2] += aV * w2; acc[i][3] += aV * w3;
      }
    }
  }

  for (int i = 0; i < 8; i++) {
    int rl = row0 + rg2 + i;
    if (rl < NPG) {
      size_t n = (size_t)g * NPG + rl;
#pragma unroll
      for (int j = 0; j < 4; j++) {
        int c = cg2 + 32 * j;
        if (c < KPG)
          assign_out[n * KPG + c] = frelu(acc[i][j] + b2p[g * KPG + c]);
      }
    }
  }
}

// ---------------------------------------------------------------------------
// Masked softmax over the 100 active cols (reference-exact renormalization).
// ---------------------------------------------------------------------------
__global__ __launch_bounds__(256) void softmax100(float* __restrict__ assign) {
  int n = blockIdx.x * 4 + (threadIdx.x >> 6);
  int lane = threadIdx.x & 63;
  float* row = assign + (size_t)n * KPG;
  float v1 = row[lane];
  bool has2 = lane < (KPG - 64);
  float v2 = has2 ? row[64 + lane] : 0.0f;
  float m = fmaxf(fmaxf(v1, v2), 0.0f);
#pragma unroll
  for (int o = 32; o > 0; o >>= 1) m = fmaxf(m, __shfl_xor(m, o));
  float e1 = expf(v1 - m);
  float e2 = has2 ? expf(v2 - m) : 0.0f;
  float s = e1 + e2;
#pragma unroll
  for (int o = 32; o > 0; o >>= 1) s += __shfl_xor(s, o);
  float denom = s + (float)(K_ASSIGN - KPG) * expf(-m);
  float scale = 1.0f / (s + 1e-13f * denom);
  row[lane] = e1 * scale;
  if (has2) row[64 + lane] = e2 * scale;
}

// ---------------------------------------------------------------------------
// h_pool[g*100+k1][d] = sum_n assign[n][k1] * feat[n][d]  per graph.
// ---------------------------------------------------------------------------
__global__ __launch_bounds__(256) void pool_gemm(
    const float* __restrict__ assign, const float* __restrict__ feat,
    float* __restrict__ out_hpool) {
  __shared__ float as[25][101];
  __shared__ float fs[25][129];
  int g = blockIdx.x >> 4, ch = blockIdx.x & 15;
  int nbase0 = g * NPG + ch * 125;
  int t = threadIdx.x;
  int a = t >> 4, b = t & 15;
  float acc[7][8] = {};
  for (int tile = 0; tile < 5; tile++) {
    int nb = nbase0 + tile * 25;
    __syncthreads();
    for (int i = 0; i < 10; i++) {
      int idx = t + i * 256;
      if (idx < 2500) {
        int r = idx / 100, c = idx % 100;
        as[r][c] = assign[(size_t)(nb + r) * KPG + c];
      }
    }
    for (int i = 0; i < 13; i++) {
      int idx = t + i * 256;
      if (idx < 3200) {
        int r = idx >> 7, c = idx & 127;
        fs[r][c] = feat[(size_t)(nb + r) * 128 + c];
      }
    }
    __syncthreads();
    for (int n = 0; n < 25; n++) {
      float av[7], fv[8];
#pragma unroll
      for (int i = 0; i < 7; i++) {
        int k1 = a + 16 * i;
        av[i] = (k1 < KPG) ? as[n][k1] : 0.0f;
      }
#pragma unroll
      for (int j = 0; j < 8; j++) fv[j] = fs[n][b + 16 * j];
#pragma unroll
      for (int i = 0; i < 7; i++)
#pragma unroll
        for (int j = 0; j < 8; j++) acc[i][j] += av[i] * fv[j];
    }
  }
  for (int i = 0; i < 7; i++) {
    int k1 = a + 16 * i;
    if (k1 < KPG)
      for (int j = 0; j < 8; j++)
        atomicAdd(out_hpool + (size_t)(g * KPG + k1) * 128 + b + 16 * j,
                  acc[i][j]);
  }
}

// ---------------------------------------------------------------------------
// adj block-diagonal: adj[g*100+k1][g*100+k2] = sum_n assign[n][k1]*tmp[n][k2]
// ---------------------------------------------------------------------------
__global__ __launch_bounds__(256) void adj_gemm(
    const float* __restrict__ assign, const float* __restrict__ tmp,
    float* __restrict__ out_adj) {
  __shared__ float as[25][101];
  __shared__ float ts[25][101];
  int g = blockIdx.x >> 4, ch = blockIdx.x & 15;
  int nbase0 = g * NPG + ch * 125;
  int t = threadIdx.x;
  int a = t >> 4, b = t & 15;
  float acc[7][7] = {};
  for (int tile = 0; tile < 5; tile++) {
    int nb = nbase0 + tile * 25;
    __syncthreads();
    for (int i = 0; i < 10; i++) {
      int idx = t + i * 256;
      if (idx < 2500) {
        int r = idx / 100, c = idx % 100;
        as[r][c] = assign[(size_t)(nb + r) * KPG + c];
        ts[r][c] = tmp[(size_t)(nb + r) * KPG + c];
      }
    }
    __syncthreads();
    for (int n = 0; n < 25; n++) {
      float av[7], tv[7];
#pragma unroll
      for (int i = 0; i < 7; i++) {
        int k1 = a + 16 * i;
        av[i] = (k1 < KPG) ? as[n][k1] : 0.0f;
      }
#pragma unroll
      for (int j = 0; j < 7; j++) {
        int k2 = b + 16 * j;
        tv[j] = (k2 < KPG) ? ts[n][k2] : 0.0f;
      }
#pragma unroll
      for (int i = 0; i < 7; i++)
#pragma unroll
        for (int j = 0; j < 7; j++) acc[i][j] += av[i] * tv[j];
    }
  }
  for (int i = 0; i < 7; i++) {
    int k1 = a + 16 * i;
    if (k1 >= KPG) continue;
    for (int j = 0; j < 7; j++) {
      int k2 = b + 16 * j;
      if (k2 < KPG)
        atomicAdd(out_adj + (size_t)(g * KPG + k1) * K_ASSIGN + g * KPG + k2,
                  acc[i][j]);
    }
  }
}

extern "C" void kernel_launch(void* const* d_in, const int* in_sizes, int n_in,
                              void* d_out, int out_size, void* d_ws,
                              size_t ws_size, hipStream_t stream) {
  (void)in_sizes; (void)n_in; (void)ws_size;
  const float* h   = (const float*)d_in[0];
  const int*   src = (const int*)d_in[1];
  const int*   dst = (const int*)d_in[2];
  const float* W1f = (const float*)d_in[3];
  const float* b1f = (const float*)d_in[4];
  const float* W2f = (const float*)d_in[5];
  const float* b2f = (const float*)d_in[6];
  const float* W1p = (const float*)d_in[7];
  const float* b1p = (const float*)d_in[8];
  const float* W2p = (const float*)d_in[9];
  const float* b2p = (const float*)d_in[10];

  float* out_adj   = (float*)d_out;
  float* out_hpool = out_adj + (size_t)K_ASSIGN * K_ASSIGN;

  char* ws = (char*)d_ws;
  int*   deg_cnt  = (int*)(ws + 0);            //    128,000 B
  int*   rowstart = (int*)(ws + 128000);       //    128,016 B (32001 ints)
  int*   cursor   = (int*)(ws + 256064);       //    128,000 B
  int*   bucket   = (int*)(ws + 384064);       //  2,048,000 B
  float* x        = (float*)(ws + 2432064);    // 16,384,000 B
  float* x1f      = (float*)(ws + 18816064);   // 16,384,000 B
  float* feat     = (float*)(ws + 35200064);   // 16,384,000 B
  float* assign   = (float*)(ws + 51584064);   // 12,800,000 B
  float* tmp      = (float*)(ws + 64384064);   // 12,800,000 B  (end ~77.2 MB)

  hipMemsetAsync(deg_cnt, 0, 128000, stream);
  hipMemsetAsync(cursor, 0, 128000, stream);
  hipMemsetAsync(d_out, 0, (size_t)out_size * sizeof(float), stream);

  // CSR build (by dst)
  edge_hist<<<N_EDGES / 256, 256, 0, stream>>>(dst, deg_cnt);
  scan_counts<<<1, 256, 0, stream>>>(deg_cnt, rowstart);
  edge_fill<<<N_EDGES / 256, 256, 0, stream>>>(src, dst, rowstart, cursor, bucket);

  // aggregation (gather) + x = h + agg/deg
  gin_gather<<<N_NODES / 4, 256, 0, stream>>>(rowstart, bucket, h, x);

  // feat path
  gemm_d128<<<N_NODES / 64, 256, 0, stream>>>(x, W1f, b1f, x1f);
  gemm_d128<<<N_NODES / 64, 256, 0, stream>>>(x1f, W2f, b2f, feat);

  // assign path
  fused_assign<<<512, 256, 0, stream>>>(x, W1p, b1p, W2p, b2p, assign);
  softmax100<<<N_NODES / 4, 256, 0, stream>>>(assign);

  // adj @ assign via gather
  tmp_gather<<<N_NODES / 4, 256, 0, stream>>>(rowstart, bucket, assign, tmp);

  // outputs
  pool_gemm<<<NGRAPH * 16, 256, 0, stream>>>(assign, feat, out_hpool);
  adj_gemm<<<NGRAPH * 16, 256, 0, stream>>>(assign, tmp, out_adj);
}

// Round 3
// 344.608 us; speedup vs baseline: 6.9643x; 2.4161x over previous
//
#include <hip/hip_runtime.h>

#define N_NODES 32000
#define NPG     2000
#define NGRAPH  16
#define K_ASSIGN 1600
#define KPG     100
#define D_FEAT  128
#define N_EDGES 512000

typedef float f32x4 __attribute__((ext_vector_type(4)));
typedef __bf16 bf16x8 __attribute__((ext_vector_type(8)));

__device__ __forceinline__ float frelu(float v) { return fmaxf(v, 0.0f); }

__device__ __forceinline__ unsigned short f2bf(float f) {
  unsigned u = __float_as_uint(f);
  u += 0x7FFFu + ((u >> 16) & 1u);
  return (unsigned short)(u >> 16);
}

// LDS swizzle: XOR byte bits 4-6 with (row&7)  -> in ushort units: bits 3-5.
__device__ __forceinline__ int SW(int row, int us) { return us ^ ((row & 7) << 3); }

// ---------------------------------------------------------------------------
// CSR build: histogram of dst
// ---------------------------------------------------------------------------
__global__ __launch_bounds__(256) void edge_hist(
    const int* __restrict__ dst, int* __restrict__ cnt) {
  int e = blockIdx.x * 256 + threadIdx.x;
  if (e < N_EDGES) atomicAdd(&cnt[dst[e]], 1);
}

__global__ __launch_bounds__(256) void scan_counts(
    const int* __restrict__ cnt, int* __restrict__ rowstart) {
  __shared__ int sums[256];
  int t = threadIdx.x;
  int base = t * 125;
  int s = 0;
  for (int i = 0; i < 125; i++) s += cnt[base + i];
  sums[t] = s;
  __syncthreads();
  for (int off = 1; off < 256; off <<= 1) {
    int v = (t >= off) ? sums[t - off] : 0;
    __syncthreads();
    sums[t] += v;
    __syncthreads();
  }
  int run = (t == 0) ? 0 : sums[t - 1];
  for (int i = 0; i < 125; i++) {
    rowstart[base + i] = run;
    run += cnt[base + i];
  }
  if (t == 255) rowstart[32000] = run;
}

__global__ __launch_bounds__(256) void edge_fill(
    const int* __restrict__ src, const int* __restrict__ dst,
    const int* __restrict__ rowstart, int* __restrict__ cursor,
    int* __restrict__ bucket) {
  int e = blockIdx.x * 256 + threadIdx.x;
  if (e < N_EDGES) {
    int d = dst[e];
    int pos = atomicAdd(&cursor[d], 1);
    bucket[rowstart[d] + pos] = src[e];
  }
}

// ---------------------------------------------------------------------------
// Gather aggregation + compute_x, emitting bf16: x[n] = h[n] + mean h[src]
// ---------------------------------------------------------------------------
__global__ __launch_bounds__(256) void gin_gather(
    const int* __restrict__ rowstart, const int* __restrict__ bucket,
    const float* __restrict__ h, unsigned short* __restrict__ x_bf) {
  int n = blockIdx.x * 4 + (threadIdx.x >> 6);
  int lane = threadIdx.x & 63;
  int rs = rowstart[n], re = rowstart[n + 1];
  const float2* h2 = (const float2*)h;
  float2 acc = make_float2(0.f, 0.f);
  int e = rs;
  for (; e + 4 <= re; e += 4) {
    int s0 = bucket[e], s1 = bucket[e + 1], s2 = bucket[e + 2], s3 = bucket[e + 3];
    float2 a0 = h2[(size_t)s0 * 64 + lane];
    float2 a1 = h2[(size_t)s1 * 64 + lane];
    float2 a2 = h2[(size_t)s2 * 64 + lane];
    float2 a3 = h2[(size_t)s3 * 64 + lane];
    acc.x += (a0.x + a1.x) + (a2.x + a3.x);
    acc.y += (a0.y + a1.y) + (a2.y + a3.y);
  }
  for (; e < re; e++) {
    int s0 = bucket[e];
    float2 a0 = h2[(size_t)s0 * 64 + lane];
    acc.x += a0.x;
    acc.y += a0.y;
  }
  float invd = 1.0f / fmaxf((float)(re - rs), 1.0f);
  float2 hv = h2[(size_t)n * 64 + lane];
  ushort2 o;
  o.x = f2bf(hv.x + acc.x * invd);
  o.y = f2bf(hv.y + acc.y * invd);
  ((ushort2*)x_bf)[(size_t)n * 64 + lane] = o;
}

// ---------------------------------------------------------------------------
// Transpose+convert: out[c][r] = bf16(in[r][c]); R, C multiples of 32.
// ---------------------------------------------------------------------------
__global__ __launch_bounds__(256) void transpose_bf(
    const float* __restrict__ in, unsigned short* __restrict__ out,
    int R, int C) {
  __shared__ float tile[32][33];
  int ct = C >> 5;
  int bc = blockIdx.x % ct, br = blockIdx.x / ct;
  int r0 = br * 32, c0 = bc * 32;
  int t = threadIdx.x;
#pragma unroll
  for (int i = 0; i < 4; i++) {
    int r = (t >> 5) + i * 8, c = t & 31;
    tile[r][c] = in[(size_t)(r0 + r) * C + c0 + c];
  }
  __syncthreads();
#pragma unroll
  for (int i = 0; i < 4; i++) {
    int c = (t >> 5) + i * 8, r = t & 31;
    out[(size_t)(c0 + c) * R + r0 + r] = f2bf(tile[r][c]);
  }
}

// ---------------------------------------------------------------------------
// MFMA GEMM: out = relu(A[64xN? rows x128] @ W + b), W given as WT[c][k] bf16.
// Block = 64 rows, 4 waves; wave = 16 rows x 128 cols.
// ---------------------------------------------------------------------------
template <bool OUT_BF16>
__global__ __launch_bounds__(256) void gemm128_mfma(
    const unsigned short* __restrict__ A, const unsigned short* __restrict__ WT,
    const float* __restrict__ bias, void* __restrict__ out) {
  __shared__ unsigned short at[64 * 128];
  __shared__ unsigned short wt[128 * 128];
  int t = threadIdx.x;
  size_t base = (size_t)blockIdx.x * 64 * 128;
#pragma unroll
  for (int i = 0; i < 4; i++) {
    int fi = t + 256 * i;
    int r = fi >> 4, u8 = (fi & 15) * 8;
    *(uint4*)&at[r * 128 + SW(r, u8)] = *(const uint4*)(A + base + r * 128 + u8);
  }
#pragma unroll
  for (int i = 0; i < 8; i++) {
    int fi = t + 256 * i;
    int r = fi >> 4, u8 = (fi & 15) * 8;
    *(uint4*)&wt[r * 128 + SW(r, u8)] = *(const uint4*)(WT + r * 128 + u8);
  }
  __syncthreads();

  int w = t >> 6, l = t & 63;
  int lr = l & 15, lg = l >> 4;
  bf16x8 af[4];
#pragma unroll
  for (int kc = 0; kc < 4; kc++) {
    int row = 16 * w + lr;
    af[kc] = *(bf16x8*)&at[row * 128 + SW(row, 32 * kc + 8 * lg)];
  }
  f32x4 acc[8];
#pragma unroll
  for (int nt = 0; nt < 8; nt++) acc[nt] = (f32x4){0.f, 0.f, 0.f, 0.f};
#pragma unroll
  for (int nt = 0; nt < 8; nt++) {
    int c = 16 * nt + lr;
#pragma unroll
    for (int kc = 0; kc < 4; kc++) {
      bf16x8 bf = *(bf16x8*)&wt[c * 128 + SW(c, 32 * kc + 8 * lg)];
      acc[nt] = __builtin_amdgcn_mfma_f32_16x16x32_bf16(af[kc], bf, acc[nt], 0, 0, 0);
    }
  }
#pragma unroll
  for (int nt = 0; nt < 8; nt++) {
    int col = 16 * nt + lr;
    float bv = bias[col];
#pragma unroll
    for (int r = 0; r < 4; r++) {
      size_t n = base / 128 + 16 * w + 4 * lg + r;
      float v = frelu(acc[nt][r] + bv);
      if (OUT_BF16)
        ((unsigned short*)out)[n * 128 + col] = f2bf(v);
      else
        ((float*)out)[n * 128 + col] = v;
    }
  }
}

// ---------------------------------------------------------------------------
// Fused assign path, MFMA. Block = 64 rows of one graph, 4 waves.
// per 64-wide K-chunk: P[64x64] = relu(x@W1p_chunk + b1p) -> bf16 LDS;
//                      acc[64x112] += P @ W2p_chunk (only in-graph cols).
// ---------------------------------------------------------------------------
__global__ __launch_bounds__(256) void fused_assign_mfma(
    const unsigned short* __restrict__ x_bf, const unsigned short* __restrict__ w1t,
    const float* __restrict__ b1p, const unsigned short* __restrict__ w2t,
    const float* __restrict__ b2p, float* __restrict__ assign_out) {
  __shared__ unsigned short xt[64 * 128];   // 16 KB
  __shared__ unsigned short w1s[64 * 128];  // 16 KB  [c][k]
  __shared__ unsigned short ps[64 * 64];    //  8 KB  [row][kk]
  __shared__ unsigned short w2s[112 * 64];  // 14 KB  [c][kk]
  int t = threadIdx.x;
  int g = blockIdx.x >> 5;
  int row0 = (blockIdx.x & 31) << 6;
  int n0 = g * NPG + row0;

#pragma unroll
  for (int i = 0; i < 4; i++) {
    int fi = t + 256 * i;
    int r = fi >> 4, u8 = (fi & 15) * 8;
    uint4 v = make_uint4(0, 0, 0, 0);
    if (row0 + r < NPG) v = *(const uint4*)(x_bf + (size_t)(n0 + r) * 128 + u8);
    *(uint4*)&xt[r * 128 + SW(r, u8)] = v;
  }
  __syncthreads();

  int w = t >> 6, l = t & 63;
  int lr = l & 15, lg = l >> 4;
  bf16x8 af[4];
#pragma unroll
  for (int kc = 0; kc < 4; kc++) {
    int row = 16 * w + lr;
    af[kc] = *(bf16x8*)&xt[row * 128 + SW(row, 32 * kc + 8 * lg)];
  }
  f32x4 acc[7];
#pragma unroll
  for (int nt = 0; nt < 7; nt++) acc[nt] = (f32x4){0.f, 0.f, 0.f, 0.f};

  for (int k0 = 0; k0 < K_ASSIGN; k0 += 64) {
    __syncthreads();  // prev chunk done reading w1s/w2s/ps
    // stage W1p chunk: w1s[c][k] = w1t[k0+c][k], c<64, k<128
#pragma unroll
    for (int i = 0; i < 4; i++) {
      int fi = t + 256 * i;
      int c = fi >> 4, u8 = (fi & 15) * 8;
      *(uint4*)&w1s[c * 128 + SW(c, u8)] =
          *(const uint4*)(w1t + (size_t)(k0 + c) * 128 + u8);
    }
    // stage W2p chunk: w2s[c][kk] = w2t[g*100+c][k0+kk], c<112 (pad>=100), kk<64
#pragma unroll
    for (int i = 0; i < 4; i++) {
      int fi = t + 256 * i;
      if (fi < 896) {
        int c = fi >> 3, u8 = (fi & 7) * 8;
        uint4 v = make_uint4(0, 0, 0, 0);
        if (c < KPG)
          v = *(const uint4*)(w2t + (size_t)(g * KPG + c) * K_ASSIGN + k0 + u8);
        *(uint4*)&w2s[c * 64 + SW(c, u8)] = v;
      }
    }
    __syncthreads();

    // phase 1: P = relu(x @ W1p_chunk + b1p)
    f32x4 p[4];
#pragma unroll
    for (int nt = 0; nt < 4; nt++) {
      p[nt] = (f32x4){0.f, 0.f, 0.f, 0.f};
      int c = 16 * nt + lr;
#pragma unroll
      for (int kc = 0; kc < 4; kc++) {
        bf16x8 bf = *(bf16x8*)&w1s[c * 128 + SW(c, 32 * kc + 8 * lg)];
        p[nt] = __builtin_amdgcn_mfma_f32_16x16x32_bf16(af[kc], bf, p[nt], 0, 0, 0);
      }
    }
    // bias + relu + cvt bf16 -> ps[row][kk]
#pragma unroll
    for (int nt = 0; nt < 4; nt++) {
      int kk = 16 * nt + lr;
      float b1 = b1p[k0 + kk];
#pragma unroll
      for (int r = 0; r < 4; r++) {
        int row = 16 * w + 4 * lg + r;
        ps[row * 64 + (kk ^ ((row & 7) << 3))] = f2bf(frelu(p[nt][r] + b1));
      }
    }
    __syncthreads();

    // phase 2: acc += P @ W2p_chunk
    bf16x8 pa[2];
#pragma unroll
    for (int kc = 0; kc < 2; kc++) {
      int row = 16 * w + lr;
      pa[kc] = *(bf16x8*)&ps[row * 64 + ((32 * kc + 8 * lg) ^ ((row & 7) << 3))];
    }
#pragma unroll
    for (int nt = 0; nt < 7; nt++) {
      int c = 16 * nt + lr;
#pragma unroll
      for (int kc = 0; kc < 2; kc++) {
        bf16x8 bf = *(bf16x8*)&w2s[c * 64 + ((32 * kc + 8 * lg) ^ ((c & 7) << 3))];
        acc[nt] = __builtin_amdgcn_mfma_f32_16x16x32_bf16(pa[kc], bf, acc[nt], 0, 0, 0);
      }
    }
  }

  // epilogue: bias + relu, store f32 logits (100 active cols)
#pragma unroll
  for (int nt = 0; nt < 7; nt++) {
    int col = 16 * nt + lr;
    if (col < KPG) {
      float bv = b2p[g * KPG + col];
#pragma unroll
      for (int r = 0; r < 4; r++) {
        int rowl = row0 + 16 * w + 4 * lg + r;
        if (rowl < NPG)
          assign_out[((size_t)g * NPG + rowl) * KPG + col] = frelu(acc[nt][r] + bv);
      }
    }
  }
}

// ---------------------------------------------------------------------------
// Masked softmax over the 100 active cols (reference-exact renormalization).
// ---------------------------------------------------------------------------
__global__ __launch_bounds__(256) void softmax100(float* __restrict__ assign) {
  int n = blockIdx.x * 4 + (threadIdx.x >> 6);
  int lane = threadIdx.x & 63;
  float* row = assign + (size_t)n * KPG;
  float v1 = row[lane];
  bool has2 = lane < (KPG - 64);
  float v2 = has2 ? row[64 + lane] : 0.0f;
  float m = fmaxf(fmaxf(v1, v2), 0.0f);
#pragma unroll
  for (int o = 32; o > 0; o >>= 1) m = fmaxf(m, __shfl_xor(m, o));
  float e1 = expf(v1 - m);
  float e2 = has2 ? expf(v2 - m) : 0.0f;
  float s = e1 + e2;
#pragma unroll
  for (int o = 32; o > 0; o >>= 1) s += __shfl_xor(s, o);
  float denom = s + (float)(K_ASSIGN - KPG) * expf(-m);
  float scale = 1.0f / (s + 1e-13f * denom);
  row[lane] = e1 * scale;
  if (has2) row[64 + lane] = e2 * scale;
}

// ---------------------------------------------------------------------------
// tmp[n] = sum_{e->n} assign[src_e]  (100-wide). One wave/node, 50 lanes.
// ---------------------------------------------------------------------------
__global__ __launch_bounds__(256) void tmp_gather(
    const int* __restrict__ rowstart, const int* __restrict__ bucket,
    const float* __restrict__ assign, float* __restrict__ tmp) {
  int n = blockIdx.x * 4 + (threadIdx.x >> 6);
  int lane = threadIdx.x & 63;
  if (lane >= 50) return;
  int rs = rowstart[n], re = rowstart[n + 1];
  float2 acc = make_float2(0.f, 0.f);
  int e = rs;
  for (; e + 2 <= re; e += 2) {
    int s0 = bucket[e], s1 = bucket[e + 1];
    float2 a0 = *(const float2*)(assign + (size_t)s0 * KPG + lane * 2);
    float2 a1 = *(const float2*)(assign + (size_t)s1 * KPG + lane * 2);
    acc.x += a0.x + a1.x;
    acc.y += a0.y + a1.y;
  }
  for (; e < re; e++) {
    int s0 = bucket[e];
    float2 a0 = *(const float2*)(assign + (size_t)s0 * KPG + lane * 2);
    acc.x += a0.x;
    acc.y += a0.y;
  }
  *(float2*)(tmp + (size_t)n * KPG + lane * 2) = acc;
}

// ---------------------------------------------------------------------------
// h_pool[g*100+k1][d] = sum_n assign[n][k1] * feat[n][d]  per graph.
// ---------------------------------------------------------------------------
__global__ __launch_bounds__(256) void pool_gemm(
    const float* __restrict__ assign, const float* __restrict__ feat,
    float* __restrict__ out_hpool) {
  __shared__ float as[25][101];
  __shared__ float fs[25][129];
  int g = blockIdx.x >> 4, ch = blockIdx.x & 15;
  int nbase0 = g * NPG + ch * 125;
  int t = threadIdx.x;
  int a = t >> 4, b = t & 15;
  float acc[7][8] = {};
  for (int tile = 0; tile < 5; tile++) {
    int nb = nbase0 + tile * 25;
    __syncthreads();
    for (int i = 0; i < 10; i++) {
      int idx = t + i * 256;
      if (idx < 2500) {
        int r = idx / 100, c = idx % 100;
        as[r][c] = assign[(size_t)(nb + r) * KPG + c];
      }
    }
    for (int i = 0; i < 13; i++) {
      int idx = t + i * 256;
      if (idx < 3200) {
        int r = idx >> 7, c = idx & 127;
        fs[r][c] = feat[(size_t)(nb + r) * 128 + c];
      }
    }
    __syncthreads();
    for (int n = 0; n < 25; n++) {
      float av[7], fv[8];
#pragma unroll
      for (int i = 0; i < 7; i++) {
        int k1 = a + 16 * i;
        av[i] = (k1 < KPG) ? as[n][k1] : 0.0f;
      }
#pragma unroll
      for (int j = 0; j < 8; j++) fv[j] = fs[n][b + 16 * j];
#pragma unroll
      for (int i = 0; i < 7; i++)
#pragma unroll
        for (int j = 0; j < 8; j++) acc[i][j] += av[i] * fv[j];
    }
  }
  for (int i = 0; i < 7; i++) {
    int k1 = a + 16 * i;
    if (k1 < KPG)
      for (int j = 0; j < 8; j++)
        atomicAdd(out_hpool + (size_t)(g * KPG + k1) * 128 + b + 16 * j,
                  acc[i][j]);
  }
}

// ---------------------------------------------------------------------------
// adj block-diagonal: adj[g*100+k1][g*100+k2] = sum_n assign[n][k1]*tmp[n][k2]
// ---------------------------------------------------------------------------
__global__ __launch_bounds__(256) void adj_gemm(
    const float* __restrict__ assign, const float* __restrict__ tmp,
    float* __restrict__ out_adj) {
  __shared__ float as[25][101];
  __shared__ float ts[25][101];
  int g = blockIdx.x >> 4, ch = blockIdx.x & 15;
  int nbase0 = g * NPG + ch * 125;
  int t = threadIdx.x;
  int a = t >> 4, b = t & 15;
  float acc[7][7] = {};
  for (int tile = 0; tile < 5; tile++) {
    int nb = nbase0 + tile * 25;
    __syncthreads();
    for (int i = 0; i < 10; i++) {
      int idx = t + i * 256;
      if (idx < 2500) {
        int r = idx / 100, c = idx % 100;
        as[r][c] = assign[(size_t)(nb + r) * KPG + c];
        ts[r][c] = tmp[(size_t)(nb + r) * KPG + c];
      }
    }
    __syncthreads();
    for (int n = 0; n < 25; n++) {
      float av[7], tv[7];
#pragma unroll
      for (int i = 0; i < 7; i++) {
        int k1 = a + 16 * i;
        av[i] = (k1 < KPG) ? as[n][k1] : 0.0f;
      }
#pragma unroll
      for (int j = 0; j < 7; j++) {
        int k2 = b + 16 * j;
        tv[j] = (k2 < KPG) ? ts[n][k2] : 0.0f;
      }
#pragma unroll
      for (int i = 0; i < 7; i++)
#pragma unroll
        for (int j = 0; j < 7; j++) acc[i][j] += av[i] * tv[j];
    }
  }
  for (int i = 0; i < 7; i++) {
    int k1 = a + 16 * i;
    if (k1 >= KPG) continue;
    for (int j = 0; j < 7; j++) {
      int k2 = b + 16 * j;
      if (k2 < KPG)
        atomicAdd(out_adj + (size_t)(g * KPG + k1) * K_ASSIGN + g * KPG + k2,
                  acc[i][j]);
    }
  }
}

extern "C" void kernel_launch(void* const* d_in, const int* in_sizes, int n_in,
                              void* d_out, int out_size, void* d_ws,
                              size_t ws_size, hipStream_t stream) {
  (void)in_sizes; (void)n_in; (void)ws_size;
  const float* h   = (const float*)d_in[0];
  const int*   src = (const int*)d_in[1];
  const int*   dst = (const int*)d_in[2];
  const float* W1f = (const float*)d_in[3];
  const float* b1f = (const float*)d_in[4];
  const float* W2f = (const float*)d_in[5];
  const float* b2f = (const float*)d_in[6];
  const float* W1p = (const float*)d_in[7];
  const float* b1p = (const float*)d_in[8];
  const float* W2p = (const float*)d_in[9];
  const float* b2p = (const float*)d_in[10];

  float* out_adj   = (float*)d_out;
  float* out_hpool = out_adj + (size_t)K_ASSIGN * K_ASSIGN;

  char* ws = (char*)d_ws;
  int*   deg_cnt  = (int*)(ws + 0);                     //   128,000
  int*   rowstart = (int*)(ws + 128000);                //   128,016
  int*   cursor   = (int*)(ws + 256032);                //   128,000
  int*   bucket   = (int*)(ws + 384032);                // 2,048,000
  unsigned short* x_bf   = (unsigned short*)(ws + 2432032);   // 8,192,000
  unsigned short* x1f_bf = (unsigned short*)(ws + 10624032);  // 8,192,000
  float* feat   = (float*)(ws + 18816032);              // 16,384,000
  float* assign = (float*)(ws + 35200032);              // 12,800,000
  float* tmp    = (float*)(ws + 48000032);              // 12,800,000
  unsigned short* w1f_t = (unsigned short*)(ws + 60800032);   //    32,768
  unsigned short* w2f_t = (unsigned short*)(ws + 60832800);   //    32,768
  unsigned short* w1p_t = (unsigned short*)(ws + 60865568);   //   409,600
  unsigned short* w2p_t = (unsigned short*)(ws + 61275168);   // 5,120,000

  hipMemsetAsync(deg_cnt, 0, 128000, stream);
  hipMemsetAsync(cursor, 0, 128000, stream);
  hipMemsetAsync(d_out, 0, (size_t)out_size * sizeof(float), stream);

  // CSR build (by dst)
  edge_hist<<<N_EDGES / 256, 256, 0, stream>>>(dst, deg_cnt);
  scan_counts<<<1, 256, 0, stream>>>(deg_cnt, rowstart);
  edge_fill<<<N_EDGES / 256, 256, 0, stream>>>(src, dst, rowstart, cursor, bucket);

  // aggregation (gather) -> x in bf16
  gin_gather<<<N_NODES / 4, 256, 0, stream>>>(rowstart, bucket, h, x_bf);

  // weight transposes/conversions to bf16 [col][k]
  transpose_bf<<<16, 256, 0, stream>>>(W1f, w1f_t, 128, 128);
  transpose_bf<<<16, 256, 0, stream>>>(W2f, w2f_t, 128, 128);
  transpose_bf<<<(128 / 32) * (K_ASSIGN / 32), 256, 0, stream>>>(W1p, w1p_t, 128, K_ASSIGN);
  transpose_bf<<<(K_ASSIGN / 32) * (K_ASSIGN / 32), 256, 0, stream>>>(W2p, w2p_t, K_ASSIGN, K_ASSIGN);

  // feat path (MFMA)
  gemm128_mfma<true><<<N_NODES / 64, 256, 0, stream>>>(x_bf, w1f_t, b1f, x1f_bf);
  gemm128_mfma<false><<<N_NODES / 64, 256, 0, stream>>>(x1f_bf, w2f_t, b2f, feat);

  // assign path (MFMA, fused 2 layers, only in-graph cols)
  fused_assign_mfma<<<512, 256, 0, stream>>>(x_bf, w1p_t, b1p, w2p_t, b2p, assign);
  softmax100<<<N_NODES / 4, 256, 0, stream>>>(assign);

  // adj @ assign via gather
  tmp_gather<<<N_NODES / 4, 256, 0, stream>>>(rowstart, bucket, assign, tmp);

  // outputs
  pool_gemm<<<NGRAPH * 16, 256, 0, stream>>>(assign, feat, out_hpool);
  adj_gemm<<<NGRAPH * 16, 256, 0, stream>>>(assign, tmp, out_adj);
}

// Round 4
// 310.649 us; speedup vs baseline: 7.7256x; 1.1093x over previous
//
#include <hip/hip_runtime.h>

#define N_NODES 32000
#define NPG     2000
#define NGRAPH  16
#define K_ASSIGN 1600
#define KPG     100
#define D_FEAT  128
#define N_EDGES 512000

typedef float f32x4 __attribute__((ext_vector_type(4)));
typedef __bf16 bf16x8 __attribute__((ext_vector_type(8)));

__device__ __forceinline__ float frelu(float v) { return fmaxf(v, 0.0f); }

__device__ __forceinline__ unsigned short f2bf(float f) {
  unsigned u = __float_as_uint(f);
  u += 0x7FFFu + ((u >> 16) & 1u);
  return (unsigned short)(u >> 16);
}
__device__ __forceinline__ float bfLO(unsigned v) { return __uint_as_float(v << 16); }
__device__ __forceinline__ float bfHI(unsigned v) { return __uint_as_float(v & 0xFFFF0000u); }

// ---------------------------------------------------------------------------
// CSR build
// ---------------------------------------------------------------------------
__global__ __launch_bounds__(256) void edge_hist(
    const int* __restrict__ dst, int* __restrict__ cnt) {
  int e = blockIdx.x * 256 + threadIdx.x;
  if (e < N_EDGES) atomicAdd(&cnt[dst[e]], 1);
}

__global__ __launch_bounds__(256) void scan_counts(
    const int* __restrict__ cnt, int* __restrict__ rowstart) {
  __shared__ int sums[256];
  int t = threadIdx.x;
  int base = t * 125;
  int s = 0;
  for (int i = 0; i < 125; i++) s += cnt[base + i];
  sums[t] = s;
  __syncthreads();
  for (int off = 1; off < 256; off <<= 1) {
    int v = (t >= off) ? sums[t - off] : 0;
    __syncthreads();
    sums[t] += v;
    __syncthreads();
  }
  int run = (t == 0) ? 0 : sums[t - 1];
  for (int i = 0; i < 125; i++) {
    rowstart[base + i] = run;
    run += cnt[base + i];
  }
  if (t == 255) rowstart[32000] = run;
}

__global__ __launch_bounds__(256) void edge_fill(
    const int* __restrict__ src, const int* __restrict__ dst,
    const int* __restrict__ rowstart, int* __restrict__ cursor,
    int* __restrict__ bucket) {
  int e = blockIdx.x * 256 + threadIdx.x;
  if (e < N_EDGES) {
    int d = dst[e];
    int pos = atomicAdd(&cursor[d], 1);
    bucket[rowstart[d] + pos] = src[e];
  }
}

// ---------------------------------------------------------------------------
// h (f32) -> bf16 copy
// ---------------------------------------------------------------------------
__global__ __launch_bounds__(256) void h_to_bf(
    const float* __restrict__ h, unsigned short* __restrict__ hb) {
  int i = blockIdx.x * 256 + threadIdx.x;  // float4 index
  float4 v = ((const float4*)h)[i];
  ushort4 o;
  o.x = f2bf(v.x); o.y = f2bf(v.y); o.z = f2bf(v.z); o.w = f2bf(v.w);
  ((ushort4*)hb)[i] = o;
}

// ---------------------------------------------------------------------------
// Gather aggregation + compute_x: x_bf[n] = bf16(h[n] + mean h_bf[src])
// One wave per node; lane = 2 feature dims (ushort2 neighbor reads).
// ---------------------------------------------------------------------------
__global__ __launch_bounds__(256) void gin_gather(
    const int* __restrict__ rowstart, const int* __restrict__ bucket,
    const float* __restrict__ h, const unsigned short* __restrict__ h_bf,
    unsigned short* __restrict__ x_bf) {
  int n = blockIdx.x * 4 + (threadIdx.x >> 6);
  int lane = threadIdx.x & 63;
  int rs = rowstart[n], re = rowstart[n + 1];
  const unsigned* hb = (const unsigned*)h_bf;
  float ax = 0.f, ay = 0.f;
  int e = rs;
  for (; e + 4 <= re; e += 4) {
    unsigned v0 = hb[(size_t)bucket[e] * 64 + lane];
    unsigned v1 = hb[(size_t)bucket[e + 1] * 64 + lane];
    unsigned v2 = hb[(size_t)bucket[e + 2] * 64 + lane];
    unsigned v3 = hb[(size_t)bucket[e + 3] * 64 + lane];
    ax += (bfLO(v0) + bfLO(v1)) + (bfLO(v2) + bfLO(v3));
    ay += (bfHI(v0) + bfHI(v1)) + (bfHI(v2) + bfHI(v3));
  }
  for (; e < re; e++) {
    unsigned v = hb[(size_t)bucket[e] * 64 + lane];
    ax += bfLO(v);
    ay += bfHI(v);
  }
  float invd = 1.0f / fmaxf((float)(re - rs), 1.0f);
  float2 hv = ((const float2*)h)[(size_t)n * 64 + lane];
  unsigned o = ((unsigned)f2bf(hv.y + ay * invd) << 16) | f2bf(hv.x + ax * invd);
  ((unsigned*)x_bf)[(size_t)n * 64 + lane] = o;
}

// ---------------------------------------------------------------------------
// All weight transposes (f32 [R][C] -> bf16 [C][R]) in one launch.
// ---------------------------------------------------------------------------
__global__ __launch_bounds__(256) void transpose_all(
    const float* __restrict__ W1f, const float* __restrict__ W2f,
    const float* __restrict__ W1p, const float* __restrict__ W2p,
    unsigned short* __restrict__ o1, unsigned short* __restrict__ o2,
    unsigned short* __restrict__ o3, unsigned short* __restrict__ o4) {
  __shared__ float tile[32][33];
  int b = blockIdx.x;
  const float* in;
  unsigned short* out;
  int R, C, rb;
  if (b < 16)       { in = W1f; out = o1; R = 128;  C = 128;  rb = b; }
  else if (b < 32)  { in = W2f; out = o2; R = 128;  C = 128;  rb = b - 16; }
  else if (b < 232) { in = W1p; out = o3; R = 128;  C = 1600; rb = b - 32; }
  else              { in = W2p; out = o4; R = 1600; C = 1600; rb = b - 232; }
  int ct = C >> 5;
  int bc = rb % ct, br = rb / ct;
  int r0 = br * 32, c0 = bc * 32;
  int t = threadIdx.x;
#pragma unroll
  for (int i = 0; i < 4; i++) {
    int r = (t >> 5) + i * 8, c = t & 31;
    tile[r][c] = in[(size_t)(r0 + r) * C + c0 + c];
  }
  __syncthreads();
#pragma unroll
  for (int i = 0; i < 4; i++) {
    int c = (t >> 5) + i * 8, r = t & 31;
    out[(size_t)(c0 + c) * R + r0 + r] = f2bf(tile[r][c]);
  }
}

// ---------------------------------------------------------------------------
// Fused feat path: feat = relu(relu(x@W1f+b1f)@W2f+b2f), bf16 out.
// 128 rows/block, 512 threads (8 waves x 16 rows). Both phases use swapped
// MFMA (mfma(W_frag, x_frag)) so outputs pack to ushort4 wide stores.
// LDS: region A = xt then x1; region B = W1 then W2 (padded stride 136).
// ---------------------------------------------------------------------------
#define FF_STR 136
__global__ __launch_bounds__(512) void feat_fused(
    const unsigned short* __restrict__ x_bf,
    const unsigned short* __restrict__ w1t, const float* __restrict__ b1f,
    const unsigned short* __restrict__ w2t, const float* __restrict__ b2f,
    unsigned short* __restrict__ feat_bf) {
  __shared__ __align__(16) unsigned char smem[2 * 34816];
  unsigned short* xa = (unsigned short*)smem;            // xt, then x1
  unsigned short* ws = (unsigned short*)(smem + 34816);  // W1, then W2
  int t = threadIdx.x;
  size_t base = (size_t)blockIdx.x * 128;

#pragma unroll
  for (int i = 0; i < 4; i++) {
    int fi = t + 512 * i;
    int r = fi >> 4, u8 = (fi & 15) * 8;
    *(uint4*)&xa[r * FF_STR + u8] = *(const uint4*)(x_bf + (base + r) * 128 + u8);
    *(uint4*)&ws[r * FF_STR + u8] = *(const uint4*)(w1t + (size_t)r * 128 + u8);
  }
  __syncthreads();

  int w = t >> 6, l = t & 63, lr = l & 15, lg = l >> 4;
  int myrow = 16 * w + lr;
  bf16x8 af[4];
#pragma unroll
  for (int kc = 0; kc < 4; kc++)
    af[kc] = *(bf16x8*)&xa[myrow * FF_STR + 32 * kc + 8 * lg];

  // phase 1: x1^T fragments (swapped)
  f32x4 p[8];
#pragma unroll
  for (int ntk = 0; ntk < 8; ntk++) {
    p[ntk] = (f32x4){0.f, 0.f, 0.f, 0.f};
    int c = 16 * ntk + lr;
#pragma unroll
    for (int kc = 0; kc < 4; kc++) {
      bf16x8 wf = *(bf16x8*)&ws[c * FF_STR + 32 * kc + 8 * lg];
      p[ntk] = __builtin_amdgcn_mfma_f32_16x16x32_bf16(wf, af[kc], p[ntk], 0, 0, 0);
    }
  }
  __syncthreads();  // xt + W1 fully read

  // write x1 (bf16) over xt; stage W2 over W1
#pragma unroll
  for (int ntk = 0; ntk < 8; ntk++) {
    int kk0 = 16 * ntk + 4 * lg;
    float4 b1 = *(const float4*)(b1f + kk0);
    ushort4 pk;
    pk.x = f2bf(frelu(p[ntk][0] + b1.x));
    pk.y = f2bf(frelu(p[ntk][1] + b1.y));
    pk.z = f2bf(frelu(p[ntk][2] + b1.z));
    pk.w = f2bf(frelu(p[ntk][3] + b1.w));
    *(ushort4*)&xa[myrow * FF_STR + kk0] = pk;
  }
#pragma unroll
  for (int i = 0; i < 4; i++) {
    int fi = t + 512 * i;
    int r = fi >> 4, u8 = (fi & 15) * 8;
    *(uint4*)&ws[r * FF_STR + u8] = *(const uint4*)(w2t + (size_t)r * 128 + u8);
  }
  __syncthreads();

  // phase 2 (swapped): feat
  bf16x8 a2[4];
#pragma unroll
  for (int kc = 0; kc < 4; kc++)
    a2[kc] = *(bf16x8*)&xa[myrow * FF_STR + 32 * kc + 8 * lg];
#pragma unroll
  for (int nt = 0; nt < 8; nt++) {
    f32x4 q = (f32x4){0.f, 0.f, 0.f, 0.f};
    int c = 16 * nt + lr;
#pragma unroll
    for (int kc = 0; kc < 4; kc++) {
      bf16x8 wf = *(bf16x8*)&ws[c * FF_STR + 32 * kc + 8 * lg];
      q = __builtin_amdgcn_mfma_f32_16x16x32_bf16(wf, a2[kc], q, 0, 0, 0);
    }
    int c0 = 16 * nt + 4 * lg;
    float4 b2 = *(const float4*)(b2f + c0);
    ushort4 pk;
    pk.x = f2bf(frelu(q[0] + b2.x));
    pk.y = f2bf(frelu(q[1] + b2.y));
    pk.z = f2bf(frelu(q[2] + b2.z));
    pk.w = f2bf(frelu(q[3] + b2.w));
    *(ushort4*)&feat_bf[(base + myrow) * 128 + c0] = pk;
  }
}

// ---------------------------------------------------------------------------
// Fused assign path. 64 rows/block (512 blocks), 4 waves.
// Per 64-wide K-chunk: P^T = relu(x@W1p+b1) via swapped MFMA -> b64 ps writes;
// acc += P@W2p (swapped) -> float4 epilogue stores.
// Double-buffered W staging with register prefetch; 2 barriers/chunk.
// ---------------------------------------------------------------------------
#define FA_WS 136  // 128+8 ushorts
#define FA_PS 72   // 64+8 ushorts
__global__ __launch_bounds__(256) void fused_assign_mfma(
    const unsigned short* __restrict__ x_bf, const unsigned short* __restrict__ w1t,
    const float* __restrict__ b1p, const unsigned short* __restrict__ w2t,
    const float* __restrict__ b2p, float* __restrict__ assign_out) {
  // regions: [0,17408) xt(64x136) UNION w1s[0]; [17408,34816) w1s[1];
  //          [34816,50944) w2s[0](112x72); [50944,67072) w2s[1];
  //          [67072,76288) ps(64x72)
  __shared__ __align__(16) unsigned char smem[76288];
  unsigned short* xt   = (unsigned short*)smem;
  unsigned short* w1sA = (unsigned short*)smem;
  unsigned short* w1sB = (unsigned short*)(smem + 17408);
  unsigned short* w2sA = (unsigned short*)(smem + 34816);
  unsigned short* w2sB = (unsigned short*)(smem + 50944);
  unsigned short* ps   = (unsigned short*)(smem + 67072);

  int t = threadIdx.x;
  int g = blockIdx.x >> 5;
  int row0 = (blockIdx.x & 31) << 6;
  int n0 = g * NPG + row0;

  // stage x tile
#pragma unroll
  for (int i = 0; i < 4; i++) {
    int fi = t + 256 * i;
    int r = fi >> 4, u8 = (fi & 15) * 8;
    uint4 v = make_uint4(0, 0, 0, 0);
    if (row0 + r < NPG) v = *(const uint4*)(x_bf + (size_t)(n0 + r) * 128 + u8);
    *(uint4*)&xt[r * FA_WS + u8] = v;
  }
  __syncthreads();
  int w = t >> 6, l = t & 63, lr = l & 15, lg = l >> 4;
  int myrow = 16 * w + lr;
  bf16x8 af[4];
#pragma unroll
  for (int kc = 0; kc < 4; kc++)
    af[kc] = *(bf16x8*)&xt[myrow * FA_WS + 32 * kc + 8 * lg];
  __syncthreads();  // af loaded; xt region reusable

  // stage chunk 0 into A buffers
#pragma unroll
  for (int i = 0; i < 4; i++) {
    int fi = t + 256 * i;
    int c = fi >> 4, u8 = (fi & 15) * 8;
    *(uint4*)&w1sA[c * FA_WS + u8] = *(const uint4*)(w1t + (size_t)c * 128 + u8);
  }
#pragma unroll
  for (int i = 0; i < 4; i++) {
    int fi = t + 256 * i;
    if (fi < 896) {
      int c = fi >> 3, u8 = (fi & 7) * 8;
      uint4 v = make_uint4(0, 0, 0, 0);
      if (c < KPG) v = *(const uint4*)(w2t + (size_t)(g * KPG + c) * K_ASSIGN + u8);
      *(uint4*)&w2sA[c * FA_PS + u8] = v;
    }
  }
  __syncthreads();

  unsigned short *w1c = w1sA, *w1n = w1sB, *w2c = w2sA, *w2n = w2sB;
  f32x4 acc[7];
#pragma unroll
  for (int nt = 0; nt < 7; nt++) acc[nt] = (f32x4){0.f, 0.f, 0.f, 0.f};

  for (int k0 = 0; k0 < K_ASSIGN; k0 += 64) {
    bool pf = (k0 + 64 < K_ASSIGN);
    uint4 rA[4], rB[4];
    if (pf) {
      int k1 = k0 + 64;
#pragma unroll
      for (int i = 0; i < 4; i++) {
        int fi = t + 256 * i;
        int c = fi >> 4, u8 = (fi & 15) * 8;
        rA[i] = *(const uint4*)(w1t + (size_t)(k1 + c) * 128 + u8);
      }
#pragma unroll
      for (int i = 0; i < 4; i++) {
        int fi = t + 256 * i;
        rB[i] = make_uint4(0, 0, 0, 0);
        if (fi < 896) {
          int c = fi >> 3, u8 = (fi & 7) * 8;
          if (c < KPG)
            rB[i] = *(const uint4*)(w2t + (size_t)(g * KPG + c) * K_ASSIGN + k1 + u8);
        }
      }
    }
    // phase 1 (swapped): lane holds P[kk=16ntk+4lg+r][row=myrow]
#pragma unroll
    for (int ntk = 0; ntk < 4; ntk++) {
      f32x4 p = (f32x4){0.f, 0.f, 0.f, 0.f};
      int c = 16 * ntk + lr;
#pragma unroll
      for (int kc = 0; kc < 4; kc++) {
        bf16x8 wf = *(bf16x8*)&w1c[c * FA_WS + 32 * kc + 8 * lg];
        p = __builtin_amdgcn_mfma_f32_16x16x32_bf16(wf, af[kc], p, 0, 0, 0);
      }
      int kk0 = 16 * ntk + 4 * lg;
      float4 b1 = *(const float4*)(b1p + k0 + kk0);
      ushort4 pk;
      pk.x = f2bf(frelu(p[0] + b1.x));
      pk.y = f2bf(frelu(p[1] + b1.y));
      pk.z = f2bf(frelu(p[2] + b1.z));
      pk.w = f2bf(frelu(p[3] + b1.w));
      *(ushort4*)&ps[myrow * FA_PS + kk0] = pk;
    }
    __syncthreads();  // ps ready; w1c fully read
    // phase 2 (swapped): acc[nt][r] = assign[myrow][16nt+4lg+r]
    bf16x8 pa0 = *(bf16x8*)&ps[myrow * FA_PS + 8 * lg];
    bf16x8 pa1 = *(bf16x8*)&ps[myrow * FA_PS + 32 + 8 * lg];
#pragma unroll
    for (int nt = 0; nt < 7; nt++) {
      int c = 16 * nt + lr;
      bf16x8 w0 = *(bf16x8*)&w2c[c * FA_PS + 8 * lg];
      bf16x8 w1 = *(bf16x8*)&w2c[c * FA_PS + 32 + 8 * lg];
      acc[nt] = __builtin_amdgcn_mfma_f32_16x16x32_bf16(w0, pa0, acc[nt], 0, 0, 0);
      acc[nt] = __builtin_amdgcn_mfma_f32_16x16x32_bf16(w1, pa1, acc[nt], 0, 0, 0);
    }
    // write prefetched next chunk into the other buffers
    if (pf) {
#pragma unroll
      for (int i = 0; i < 4; i++) {
        int fi = t + 256 * i;
        int c = fi >> 4, u8 = (fi & 15) * 8;
        *(uint4*)&w1n[c * FA_WS + u8] = rA[i];
      }
#pragma unroll
      for (int i = 0; i < 4; i++) {
        int fi = t + 256 * i;
        if (fi < 896) {
          int c = fi >> 3, u8 = (fi & 7) * 8;
          *(uint4*)&w2n[c * FA_PS + u8] = rB[i];
        }
      }
    }
    __syncthreads();  // next chunk staged; ps safe to rewrite
    unsigned short* s1 = w1c; w1c = w1n; w1n = s1;
    unsigned short* s2 = w2c; w2c = w2n; w2n = s2;
  }

  // epilogue: float4 stores (cols 4-aligned; 100 = 25 x float4)
  int rowl = row0 + myrow;
  if (rowl < NPG) {
#pragma unroll
    for (int nt = 0; nt < 7; nt++) {
      int col0 = 16 * nt + 4 * lg;
      if (col0 < KPG) {
        float4 b2 = *(const float4*)(b2p + g * KPG + col0);
        float4 o;
        o.x = frelu(acc[nt][0] + b2.x);
        o.y = frelu(acc[nt][1] + b2.y);
        o.z = frelu(acc[nt][2] + b2.z);
        o.w = frelu(acc[nt][3] + b2.w);
        *(float4*)(assign_out + ((size_t)g * NPG + rowl) * KPG + col0) = o;
      }
    }
  }
}

// ---------------------------------------------------------------------------
// Masked softmax over the 100 active cols; writes bf16 assign.
// ---------------------------------------------------------------------------
__global__ __launch_bounds__(256) void softmax100(
    const float* __restrict__ assign, unsigned short* __restrict__ assign_bf) {
  int n = blockIdx.x * 4 + (threadIdx.x >> 6);
  int lane = threadIdx.x & 63;
  const float* row = assign + (size_t)n * KPG;
  float v1 = row[lane];
  bool has2 = lane < (KPG - 64);
  float v2 = has2 ? row[64 + lane] : 0.0f;
  float m = fmaxf(fmaxf(v1, v2), 0.0f);
#pragma unroll
  for (int o = 32; o > 0; o >>= 1) m = fmaxf(m, __shfl_xor(m, o));
  float e1 = expf(v1 - m);
  float e2 = has2 ? expf(v2 - m) : 0.0f;
  float s = e1 + e2;
#pragma unroll
  for (int o = 32; o > 0; o >>= 1) s += __shfl_xor(s, o);
  float denom = s + (float)(K_ASSIGN - KPG) * expf(-m);
  float scale = 1.0f / (s + 1e-13f * denom);
  unsigned short* rb = assign_bf + (size_t)n * KPG;
  rb[lane] = f2bf(e1 * scale);
  if (has2) rb[64 + lane] = f2bf(e2 * scale);
}

// ---------------------------------------------------------------------------
// tmp_bf[n] = sum_{e->n} assign_bf[src_e] (100-wide). One wave/node, 50 lanes.
// ---------------------------------------------------------------------------
__global__ __launch_bounds__(256) void tmp_gather(
    const int* __restrict__ rowstart, const int* __restrict__ bucket,
    const unsigned short* __restrict__ assign_bf, unsigned short* __restrict__ tmp_bf) {
  int n = blockIdx.x * 4 + (threadIdx.x >> 6);
  int lane = threadIdx.x & 63;
  if (lane >= 50) return;
  int rs = rowstart[n], re = rowstart[n + 1];
  const unsigned* ab = (const unsigned*)assign_bf;
  float ax = 0.f, ay = 0.f;
  int e = rs;
  for (; e + 4 <= re; e += 4) {
    unsigned v0 = ab[(size_t)bucket[e] * 50 + lane];
    unsigned v1 = ab[(size_t)bucket[e + 1] * 50 + lane];
    unsigned v2 = ab[(size_t)bucket[e + 2] * 50 + lane];
    unsigned v3 = ab[(size_t)bucket[e + 3] * 50 + lane];
    ax += (bfLO(v0) + bfLO(v1)) + (bfLO(v2) + bfLO(v3));
    ay += (bfHI(v0) + bfHI(v1)) + (bfHI(v2) + bfHI(v3));
  }
  for (; e < re; e++) {
    unsigned v = ab[(size_t)bucket[e] * 50 + lane];
    ax += bfLO(v);
    ay += bfHI(v);
  }
  unsigned o = ((unsigned)f2bf(ay) << 16) | f2bf(ax);
  ((unsigned*)tmp_bf)[(size_t)n * 50 + lane] = o;
}

// ---------------------------------------------------------------------------
// pool (blocks 0..255) + adj (blocks 256..511) in one launch.
// pool: h_pool[g*100+k1][d] = sum_n assign[n][k1]*feat[n][d]
// adj : adj[g*100+k1][g*100+k2] = sum_n assign[n][k1]*tmp[n][k2]
// ---------------------------------------------------------------------------
__global__ __launch_bounds__(256) void pool_adj(
    const unsigned short* __restrict__ assign_bf,
    const unsigned short* __restrict__ feat_bf,
    const unsigned short* __restrict__ tmp_bf,
    float* __restrict__ out_adj, float* __restrict__ out_hpool) {
  __shared__ float as[25][101];
  __shared__ float bs[25][129];
  bool is_pool = blockIdx.x < 256;
  int bb = is_pool ? blockIdx.x : blockIdx.x - 256;
  int g = bb >> 4, ch = bb & 15;
  int nbase0 = g * NPG + ch * 125;
  int t = threadIdx.x;
  int a = t >> 4, b = t & 15;
  float accP[7][8] = {};
  float accA[7][7] = {};
  const unsigned* au = (const unsigned*)assign_bf;
  const unsigned* fu = (const unsigned*)feat_bf;
  const unsigned* tu = (const unsigned*)tmp_bf;
  for (int tile = 0; tile < 5; tile++) {
    int nb = nbase0 + tile * 25;
    __syncthreads();
#pragma unroll
    for (int i = 0; i < 5; i++) {
      int idx = t + i * 256;
      if (idx < 1250) {
        int r = idx / 50, cu = idx % 50;
        unsigned v = au[(size_t)(nb + r) * 50 + cu];
        as[r][cu * 2] = bfLO(v);
        as[r][cu * 2 + 1] = bfHI(v);
      }
    }
    if (is_pool) {
#pragma unroll
      for (int i = 0; i < 7; i++) {
        int idx = t + i * 256;
        if (idx < 1600) {
          int r = idx >> 6, cu = idx & 63;
          unsigned v = fu[(size_t)(nb + r) * 64 + cu];
          bs[r][cu * 2] = bfLO(v);
          bs[r][cu * 2 + 1] = bfHI(v);
        }
      }
    } else {
#pragma unroll
      for (int i = 0; i < 5; i++) {
        int idx = t + i * 256;
        if (idx < 1250) {
          int r = idx / 50, cu = idx % 50;
          unsigned v = tu[(size_t)(nb + r) * 50 + cu];
          bs[r][cu * 2] = bfLO(v);
          bs[r][cu * 2 + 1] = bfHI(v);
        }
      }
    }
    __syncthreads();
    if (is_pool) {
      for (int n = 0; n < 25; n++) {
        float av[7], fv[8];
#pragma unroll
        for (int i = 0; i < 7; i++) {
          int k1 = a + 16 * i;
          av[i] = (k1 < KPG) ? as[n][k1] : 0.0f;
        }
#pragma unroll
        for (int j = 0; j < 8; j++) fv[j] = bs[n][b + 16 * j];
#pragma unroll
        for (int i = 0; i < 7; i++)
#pragma unroll
          for (int j = 0; j < 8; j++) accP[i][j] += av[i] * fv[j];
      }
    } else {
      for (int n = 0; n < 25; n++) {
        float av[7], tv[7];
#pragma unroll
        for (int i = 0; i < 7; i++) {
          int k1 = a + 16 * i;
          av[i] = (k1 < KPG) ? as[n][k1] : 0.0f;
        }
#pragma unroll
        for (int j = 0; j < 7; j++) {
          int k2 = b + 16 * j;
          tv[j] = (k2 < KPG) ? bs[n][k2] : 0.0f;
        }
#pragma unroll
        for (int i = 0; i < 7; i++)
#pragma unroll
          for (int j = 0; j < 7; j++) accA[i][j] += av[i] * tv[j];
      }
    }
  }
  if (is_pool) {
    for (int i = 0; i < 7; i++) {
      int k1 = a + 16 * i;
      if (k1 < KPG)
        for (int j = 0; j < 8; j++)
          atomicAdd(out_hpool + (size_t)(g * KPG + k1) * 128 + b + 16 * j,
                    accP[i][j]);
    }
  } else {
    for (int i = 0; i < 7; i++) {
      int k1 = a + 16 * i;
      if (k1 >= KPG) continue;
      for (int j = 0; j < 7; j++) {
        int k2 = b + 16 * j;
        if (k2 < KPG)
          atomicAdd(out_adj + (size_t)(g * KPG + k1) * K_ASSIGN + g * KPG + k2,
                    accA[i][j]);
      }
    }
  }
}

extern "C" void kernel_launch(void* const* d_in, const int* in_sizes, int n_in,
                              void* d_out, int out_size, void* d_ws,
                              size_t ws_size, hipStream_t stream) {
  (void)in_sizes; (void)n_in; (void)ws_size;
  const float* h   = (const float*)d_in[0];
  const int*   src = (const int*)d_in[1];
  const int*   dst = (const int*)d_in[2];
  const float* W1f = (const float*)d_in[3];
  const float* b1f = (const float*)d_in[4];
  const float* W2f = (const float*)d_in[5];
  const float* b2f = (const float*)d_in[6];
  const float* W1p = (const float*)d_in[7];
  const float* b1p = (const float*)d_in[8];
  const float* W2p = (const float*)d_in[9];
  const float* b2p = (const float*)d_in[10];

  float* out_adj   = (float*)d_out;
  float* out_hpool = out_adj + (size_t)K_ASSIGN * K_ASSIGN;

  char* ws = (char*)d_ws;
  int* deg_cnt  = (int*)(ws + 0);            //   128,000
  int* rowstart = (int*)(ws + 128000);       //   128,032
  int* cursor   = (int*)(ws + 256032);       //   128,000
  int* bucket   = (int*)(ws + 384032);       // 2,048,000
  unsigned short* h_bf      = (unsigned short*)(ws + 2432032);   // 8,192,000
  unsigned short* x_bf      = (unsigned short*)(ws + 10624032);  // 8,192,000
  unsigned short* feat_bf   = (unsigned short*)(ws + 18816032);  // 8,192,000
  float*          assign    = (float*)(ws + 27008032);           // 12,800,000
  unsigned short* assign_bf = (unsigned short*)(ws + 39808032);  // 6,400,000
  unsigned short* tmp_bf    = (unsigned short*)(ws + 46208032);  // 6,400,000
  unsigned short* w1f_t     = (unsigned short*)(ws + 52608032);  //    32,768
  unsigned short* w2f_t     = (unsigned short*)(ws + 52640800);  //    32,768
  unsigned short* w1p_t     = (unsigned short*)(ws + 52673568);  //   409,600
  unsigned short* w2p_t     = (unsigned short*)(ws + 53083168);  // 5,120,000

  hipMemsetAsync(deg_cnt, 0, 128000, stream);
  hipMemsetAsync(cursor, 0, 128000, stream);
  hipMemsetAsync(d_out, 0, (size_t)out_size * sizeof(float), stream);

  // CSR build (by dst)
  edge_hist<<<N_EDGES / 256, 256, 0, stream>>>(dst, deg_cnt);
  scan_counts<<<1, 256, 0, stream>>>(deg_cnt, rowstart);
  edge_fill<<<N_EDGES / 256, 256, 0, stream>>>(src, dst, rowstart, cursor, bucket);

  // conversions / transposes
  h_to_bf<<<N_NODES * 128 / 4 / 256, 256, 0, stream>>>(h, h_bf);
  transpose_all<<<16 + 16 + 200 + 2500, 256, 0, stream>>>(
      W1f, W2f, W1p, W2p, w1f_t, w2f_t, w1p_t, w2p_t);

  // aggregation (gather) -> x in bf16
  gin_gather<<<N_NODES / 4, 256, 0, stream>>>(rowstart, bucket, h, h_bf, x_bf);

  // feat path: one fused kernel
  feat_fused<<<N_NODES / 128, 512, 0, stream>>>(x_bf, w1f_t, b1f, w2f_t, b2f, feat_bf);

  // assign path
  fused_assign_mfma<<<512, 256, 0, stream>>>(x_bf, w1p_t, b1p, w2p_t, b2p, assign);
  softmax100<<<N_NODES / 4, 256, 0, stream>>>(assign, assign_bf);

  // adj @ assign via gather
  tmp_gather<<<N_NODES / 4, 256, 0, stream>>>(rowstart, bucket, assign_bf, tmp_bf);

  // outputs
  pool_adj<<<512, 256, 0, stream>>>(assign_bf, feat_bf, tmp_bf, out_adj, out_hpool);
}

// Round 6
// 266.723 us; speedup vs baseline: 8.9979x; 1.1647x over previous
//
#include <hip/hip_runtime.h>

#define N_NODES 32000
#define NPG     2000
#define NGRAPH  16
#define K_ASSIGN 1600
#define KPG     100
#define D_FEAT  128
#define N_EDGES 512000

typedef float f32x4 __attribute__((ext_vector_type(4)));
typedef __bf16 bf16x8 __attribute__((ext_vector_type(8)));

union FragU { unsigned u[4]; bf16x8 v; };

__device__ __forceinline__ float frelu(float v) { return fmaxf(v, 0.0f); }

__device__ __forceinline__ unsigned short f2bf(float f) {
  unsigned u = __float_as_uint(f);
  u += 0x7FFFu + ((u >> 16) & 1u);
  return (unsigned short)(u >> 16);
}
__device__ __forceinline__ float bfLO(unsigned v) { return __uint_as_float(v << 16); }
__device__ __forceinline__ float bfHI(unsigned v) { return __uint_as_float(v & 0xFFFF0000u); }

// ---------------------------------------------------------------------------
// CSR build
// ---------------------------------------------------------------------------
__global__ __launch_bounds__(256) void edge_hist(
    const int* __restrict__ dst, int* __restrict__ cnt) {
  int e = blockIdx.x * 256 + threadIdx.x;
  if (e < N_EDGES) atomicAdd(&cnt[dst[e]], 1);
}

__global__ __launch_bounds__(256) void scan_counts(
    const int* __restrict__ cnt, int* __restrict__ rowstart) {
  __shared__ int sums[256];
  int t = threadIdx.x;
  int base = t * 125;
  int s = 0;
  for (int i = 0; i < 125; i++) s += cnt[base + i];
  sums[t] = s;
  __syncthreads();
  for (int off = 1; off < 256; off <<= 1) {
    int v = (t >= off) ? sums[t - off] : 0;
    __syncthreads();
    sums[t] += v;
    __syncthreads();
  }
  int run = (t == 0) ? 0 : sums[t - 1];
  for (int i = 0; i < 125; i++) {
    rowstart[base + i] = run;
    run += cnt[base + i];
  }
  if (t == 255) rowstart[32000] = run;
}

__global__ __launch_bounds__(256) void edge_fill(
    const int* __restrict__ src, const int* __restrict__ dst,
    const int* __restrict__ rowstart, int* __restrict__ cursor,
    int* __restrict__ bucket) {
  int e = blockIdx.x * 256 + threadIdx.x;
  if (e < N_EDGES) {
    int d = dst[e];
    int pos = atomicAdd(&cursor[d], 1);
    bucket[rowstart[d] + pos] = src[e];
  }
}

// ---------------------------------------------------------------------------
// h (f32) -> bf16 copy
// ---------------------------------------------------------------------------
__global__ __launch_bounds__(256) void h_to_bf(
    const float* __restrict__ h, unsigned short* __restrict__ hb) {
  int i = blockIdx.x * 256 + threadIdx.x;  // float4 index
  float4 v = ((const float4*)h)[i];
  ushort4 o;
  o.x = f2bf(v.x); o.y = f2bf(v.y); o.z = f2bf(v.z); o.w = f2bf(v.w);
  ((ushort4*)hb)[i] = o;
}

// ---------------------------------------------------------------------------
// Gather aggregation + compute_x: x_bf[n] = bf16(h[n] + mean h_bf[src])
// ---------------------------------------------------------------------------
__global__ __launch_bounds__(256) void gin_gather(
    const int* __restrict__ rowstart, const int* __restrict__ bucket,
    const float* __restrict__ h, const unsigned short* __restrict__ h_bf,
    unsigned short* __restrict__ x_bf) {
  int n = blockIdx.x * 4 + (threadIdx.x >> 6);
  int lane = threadIdx.x & 63;
  int rs = rowstart[n], re = rowstart[n + 1];
  const unsigned* hb = (const unsigned*)h_bf;
  float ax = 0.f, ay = 0.f;
  int e = rs;
  for (; e + 4 <= re; e += 4) {
    unsigned v0 = hb[(size_t)bucket[e] * 64 + lane];
    unsigned v1 = hb[(size_t)bucket[e + 1] * 64 + lane];
    unsigned v2 = hb[(size_t)bucket[e + 2] * 64 + lane];
    unsigned v3 = hb[(size_t)bucket[e + 3] * 64 + lane];
    ax += (bfLO(v0) + bfLO(v1)) + (bfLO(v2) + bfLO(v3));
    ay += (bfHI(v0) + bfHI(v1)) + (bfHI(v2) + bfHI(v3));
  }
  for (; e < re; e++) {
    unsigned v = hb[(size_t)bucket[e] * 64 + lane];
    ax += bfLO(v);
    ay += bfHI(v);
  }
  float invd = 1.0f / fmaxf((float)(re - rs), 1.0f);
  float2 hv = ((const float2*)h)[(size_t)n * 64 + lane];
  unsigned o = ((unsigned)f2bf(hv.y + ay * invd) << 16) | f2bf(hv.x + ax * invd);
  ((unsigned*)x_bf)[(size_t)n * 64 + lane] = o;
}

// ---------------------------------------------------------------------------
// All weight transposes (f32 [R][C] -> bf16 [C][R]) in one launch.
// ---------------------------------------------------------------------------
__global__ __launch_bounds__(256) void transpose_all(
    const float* __restrict__ W1f, const float* __restrict__ W2f,
    const float* __restrict__ W1p, const float* __restrict__ W2p,
    unsigned short* __restrict__ o1, unsigned short* __restrict__ o2,
    unsigned short* __restrict__ o3, unsigned short* __restrict__ o4) {
  __shared__ float tile[32][33];
  int b = blockIdx.x;
  const float* in;
  unsigned short* out;
  int R, C, rb;
  if (b < 16)       { in = W1f; out = o1; R = 128;  C = 128;  rb = b; }
  else if (b < 32)  { in = W2f; out = o2; R = 128;  C = 128;  rb = b - 16; }
  else if (b < 232) { in = W1p; out = o3; R = 128;  C = 1600; rb = b - 32; }
  else              { in = W2p; out = o4; R = 1600; C = 1600; rb = b - 232; }
  int ct = C >> 5;
  int bc = rb % ct, br = rb / ct;
  int r0 = br * 32, c0 = bc * 32;
  int t = threadIdx.x;
#pragma unroll
  for (int i = 0; i < 4; i++) {
    int r = (t >> 5) + i * 8, c = t & 31;
    tile[r][c] = in[(size_t)(r0 + r) * C + c0 + c];
  }
  __syncthreads();
#pragma unroll
  for (int i = 0; i < 4; i++) {
    int c = (t >> 5) + i * 8, r = t & 31;
    out[(size_t)(c0 + c) * R + r0 + r] = f2bf(tile[r][c]);
  }
}

// ---------------------------------------------------------------------------
// Fused feat path: feat = relu(relu(x@W1f+b1f)@W2f+b2f), bf16 out.
// ---------------------------------------------------------------------------
#define FF_STR 136
__global__ __launch_bounds__(512) void feat_fused(
    const unsigned short* __restrict__ x_bf,
    const unsigned short* __restrict__ w1t, const float* __restrict__ b1f,
    const unsigned short* __restrict__ w2t, const float* __restrict__ b2f,
    unsigned short* __restrict__ feat_bf) {
  __shared__ __align__(16) unsigned char smem[2 * 34816];
  unsigned short* xa = (unsigned short*)smem;            // xt, then x1
  unsigned short* ws = (unsigned short*)(smem + 34816);  // W1, then W2
  int t = threadIdx.x;
  size_t base = (size_t)blockIdx.x * 128;

#pragma unroll
  for (int i = 0; i < 4; i++) {
    int fi = t + 512 * i;
    int r = fi >> 4, u8 = (fi & 15) * 8;
    *(uint4*)&xa[r * FF_STR + u8] = *(const uint4*)(x_bf + (base + r) * 128 + u8);
    *(uint4*)&ws[r * FF_STR + u8] = *(const uint4*)(w1t + (size_t)r * 128 + u8);
  }
  __syncthreads();

  int w = t >> 6, l = t & 63, lr = l & 15, lg = l >> 4;
  int myrow = 16 * w + lr;
  bf16x8 af[4];
#pragma unroll
  for (int kc = 0; kc < 4; kc++)
    af[kc] = *(bf16x8*)&xa[myrow * FF_STR + 32 * kc + 8 * lg];

  // phase 1: x1^T fragments (swapped)
  f32x4 p[8];
#pragma unroll
  for (int ntk = 0; ntk < 8; ntk++) {
    p[ntk] = (f32x4){0.f, 0.f, 0.f, 0.f};
    int c = 16 * ntk + lr;
#pragma unroll
    for (int kc = 0; kc < 4; kc++) {
      bf16x8 wf = *(bf16x8*)&ws[c * FF_STR + 32 * kc + 8 * lg];
      p[ntk] = __builtin_amdgcn_mfma_f32_16x16x32_bf16(wf, af[kc], p[ntk], 0, 0, 0);
    }
  }
  __syncthreads();  // xt + W1 fully read

  // write x1 (bf16) over xt; stage W2 over W1
#pragma unroll
  for (int ntk = 0; ntk < 8; ntk++) {
    int kk0 = 16 * ntk + 4 * lg;
    float4 b1 = *(const float4*)(b1f + kk0);
    ushort4 pk;
    pk.x = f2bf(frelu(p[ntk][0] + b1.x));
    pk.y = f2bf(frelu(p[ntk][1] + b1.y));
    pk.z = f2bf(frelu(p[ntk][2] + b1.z));
    pk.w = f2bf(frelu(p[ntk][3] + b1.w));
    *(ushort4*)&xa[myrow * FF_STR + kk0] = pk;
  }
#pragma unroll
  for (int i = 0; i < 4; i++) {
    int fi = t + 512 * i;
    int r = fi >> 4, u8 = (fi & 15) * 8;
    *(uint4*)&ws[r * FF_STR + u8] = *(const uint4*)(w2t + (size_t)r * 128 + u8);
  }
  __syncthreads();

  // phase 2 (swapped): feat
  bf16x8 a2[4];
#pragma unroll
  for (int kc = 0; kc < 4; kc++)
    a2[kc] = *(bf16x8*)&xa[myrow * FF_STR + 32 * kc + 8 * lg];
#pragma unroll
  for (int nt = 0; nt < 8; nt++) {
    f32x4 q = (f32x4){0.f, 0.f, 0.f, 0.f};
    int c = 16 * nt + lr;
#pragma unroll
    for (int kc = 0; kc < 4; kc++) {
      bf16x8 wf = *(bf16x8*)&ws[c * FF_STR + 32 * kc + 8 * lg];
      q = __builtin_amdgcn_mfma_f32_16x16x32_bf16(wf, a2[kc], q, 0, 0, 0);
    }
    int c0 = 16 * nt + 4 * lg;
    float4 b2 = *(const float4*)(b2f + c0);
    ushort4 pk;
    pk.x = f2bf(frelu(q[0] + b2.x));
    pk.y = f2bf(frelu(q[1] + b2.y));
    pk.z = f2bf(frelu(q[2] + b2.z));
    pk.w = f2bf(frelu(q[3] + b2.w));
    *(ushort4*)&feat_bf[(base + myrow) * 128 + c0] = pk;
  }
}

// ---------------------------------------------------------------------------
// Fused assign path + softmax. 64 rows/block (512 blocks), 4 waves.
// Wave (rh,h): rows 32rh..+31, kk-half 32h..+31 of each 64-wide K-chunk.
// x-frags resident in VGPRs; phase-1 P stays in registers; regrouped to
// B-frag layout via __shfl. Phase-2 partial acc; cross-h reduce via LDS;
// softmax fused into epilogue (bf16 out).
// LDS double buffers addressed via smem + cur*offset (no pointer arrays —
// hipcc rejects LDS pointer-array initializers).
// ---------------------------------------------------------------------------
#define FA_WS 136  // 128+8 ushorts (pad rotates banks)
#define FA_PS 72   // 64+8 ushorts
#define FA_W1OFF 17408
#define FA_W2BASE 34816
#define FA_W2OFF 16128
__global__ __launch_bounds__(256) void fused_assign_sm(
    const unsigned short* __restrict__ x_bf, const unsigned short* __restrict__ w1t,
    const float* __restrict__ b1p, const unsigned short* __restrict__ w2t,
    const float* __restrict__ b2p, unsigned short* __restrict__ assign_bf) {
  // [0,17408) xt / w1 buf0; [17408,34816) w1 buf1;
  // [34816,50944) w2 buf0; [50944,67072) w2 buf1. Reduction reuses [0,28672).
  __shared__ __align__(16) unsigned char smem[67072];
  unsigned short* xt = (unsigned short*)smem;

  int t = threadIdx.x;
  int g = blockIdx.x >> 5;
  int row0 = (blockIdx.x & 31) << 6;
  int n0 = g * NPG + row0;

  // stage x tile (rows 0..63), zero-fill past NPG
#pragma unroll
  for (int i = 0; i < 4; i++) {
    int fi = t + 256 * i;
    int r = fi >> 4, u8 = (fi & 15) * 8;
    uint4 v = make_uint4(0, 0, 0, 0);
    if (row0 + r < NPG) v = *(const uint4*)(x_bf + (size_t)(n0 + r) * 128 + u8);
    *(uint4*)&xt[r * FA_WS + u8] = v;
  }
  __syncthreads();

  int w = t >> 6, l = t & 63, lr = l & 15, lg = l >> 4;
  int rh = w >> 1, h = w & 1;

  // resident x fragments: rows 32rh+16ct+lr, k = 32kc+8lg..+7
  bf16x8 af[2][4];
#pragma unroll
  for (int ct = 0; ct < 2; ct++)
#pragma unroll
    for (int kc = 0; kc < 4; kc++)
      af[ct][kc] =
          *(bf16x8*)&xt[(32 * rh + 16 * ct + lr) * FA_WS + 32 * kc + 8 * lg];
  __syncthreads();  // xt region becomes w1 buf0

  // stage chunk 0
  {
    unsigned short* w1s = (unsigned short*)smem;
    unsigned short* w2s = (unsigned short*)(smem + FA_W2BASE);
#pragma unroll
    for (int i = 0; i < 4; i++) {
      int fi = t + 256 * i;
      int c = fi >> 4, u8 = (fi & 15) * 8;
      *(uint4*)&w1s[c * FA_WS + u8] = *(const uint4*)(w1t + (size_t)c * 128 + u8);
    }
#pragma unroll
    for (int i = 0; i < 4; i++) {
      int fi = t + 256 * i;
      if (fi < 896) {
        int c = fi >> 3, u8 = (fi & 7) * 8;
        uint4 v = make_uint4(0, 0, 0, 0);
        if (c < KPG)
          v = *(const uint4*)(w2t + (size_t)(g * KPG + c) * K_ASSIGN + u8);
        *(uint4*)&w2s[c * FA_PS + u8] = v;
      }
    }
  }
  __syncthreads();

  f32x4 acc[7][2];
#pragma unroll
  for (int i = 0; i < 7; i++) {
    acc[i][0] = (f32x4){0.f, 0.f, 0.f, 0.f};
    acc[i][1] = (f32x4){0.f, 0.f, 0.f, 0.f};
  }

  for (int cch = 0; cch < 25; cch++) {
    int cur = cch & 1;
    int k0 = cch * 64;
    const unsigned short* w1c = (const unsigned short*)(smem + cur * FA_W1OFF);
    const unsigned short* w2c =
        (const unsigned short*)(smem + FA_W2BASE + cur * FA_W2OFF);
    bool pf = (cch < 24);
    uint4 rA[4], rB[4];
    if (pf) {  // issue next-chunk loads early (hide under MFMA phases)
      int k1 = k0 + 64;
#pragma unroll
      for (int i = 0; i < 4; i++) {
        int fi = t + 256 * i;
        int c = fi >> 4, u8 = (fi & 15) * 8;
        rA[i] = *(const uint4*)(w1t + (size_t)(k1 + c) * 128 + u8);
      }
#pragma unroll
      for (int i = 0; i < 4; i++) {
        int fi = t + 256 * i;
        rB[i] = make_uint4(0, 0, 0, 0);
        if (fi < 896) {
          int c = fi >> 3, u8 = (fi & 7) * 8;
          if (c < KPG)
            rB[i] = *(const uint4*)(w2t + (size_t)(g * KPG + c) * K_ASSIGN +
                                    k1 + u8);
        }
      }
    }

    // phase 1 (swapped): p[nt2][ct] = P^T frag, lane holds
    // P[xrow=32rh+16ct+lr][kk = 16*(2h+nt2) + 4lg + reg]
    f32x4 p[2][2];
#pragma unroll
    for (int nt2 = 0; nt2 < 2; nt2++) {
      p[nt2][0] = (f32x4){0.f, 0.f, 0.f, 0.f};
      p[nt2][1] = (f32x4){0.f, 0.f, 0.f, 0.f};
      int nt = 2 * h + nt2;
#pragma unroll
      for (int kc = 0; kc < 4; kc++) {
        bf16x8 wf = *(bf16x8*)&w1c[(16 * nt + lr) * FA_WS + 32 * kc + 8 * lg];
        p[nt2][0] = __builtin_amdgcn_mfma_f32_16x16x32_bf16(wf, af[0][kc],
                                                            p[nt2][0], 0, 0, 0);
        p[nt2][1] = __builtin_amdgcn_mfma_f32_16x16x32_bf16(wf, af[1][kc],
                                                            p[nt2][1], 0, 0, 0);
      }
    }
    // bias + relu + pack to bf16 pairs: q[nt2][ct][qi] = (kk 4lg+2qi, +1)
    unsigned q[2][2][2];
#pragma unroll
    for (int nt2 = 0; nt2 < 2; nt2++) {
      int kkb = k0 + 16 * (2 * h + nt2) + 4 * lg;
      float4 b1 = *(const float4*)(b1p + kkb);
#pragma unroll
      for (int ct = 0; ct < 2; ct++) {
        float r0 = frelu(p[nt2][ct][0] + b1.x);
        float r1 = frelu(p[nt2][ct][1] + b1.y);
        float r2 = frelu(p[nt2][ct][2] + b1.z);
        float r3 = frelu(p[nt2][ct][3] + b1.w);
        q[nt2][ct][0] = ((unsigned)f2bf(r1) << 16) | f2bf(r0);
        q[nt2][ct][1] = ((unsigned)f2bf(r3) << 16) | f2bf(r2);
      }
    }
    // regroup to B-frag layout: target (lg,m): klocal pair (8lg+2m, +1)
    // = source lane lr+16*lg' with nt2 = lg>>1, lg' = 2*(lg&1)+(m>>1), qi=m&1
    int sA = lr + 32 * (lg & 1);
    int sB = sA + 16;
    bool hi = (lg >= 2);
    FragU pa[2];
#pragma unroll
    for (int ct = 0; ct < 2; ct++) {
      unsigned a0 = (unsigned)__shfl((int)q[0][ct][0], sA, 64);
      unsigned b0 = (unsigned)__shfl((int)q[1][ct][0], sA, 64);
      unsigned a1 = (unsigned)__shfl((int)q[0][ct][1], sA, 64);
      unsigned b1u = (unsigned)__shfl((int)q[1][ct][1], sA, 64);
      unsigned a2 = (unsigned)__shfl((int)q[0][ct][0], sB, 64);
      unsigned b2u = (unsigned)__shfl((int)q[1][ct][0], sB, 64);
      unsigned a3 = (unsigned)__shfl((int)q[0][ct][1], sB, 64);
      unsigned b3u = (unsigned)__shfl((int)q[1][ct][1], sB, 64);
      pa[ct].u[0] = hi ? b0 : a0;
      pa[ct].u[1] = hi ? b1u : a1;
      pa[ct].u[2] = hi ? b2u : a2;
      pa[ct].u[3] = hi ? b3u : a3;
    }
    // phase 2: acc[ct2][ct] += W2^T-frag @ P-frag over klocal 0..31
#pragma unroll
    for (int ct2 = 0; ct2 < 7; ct2++) {
      bf16x8 wv = *(bf16x8*)&w2c[(16 * ct2 + lr) * FA_PS + 32 * h + 8 * lg];
      acc[ct2][0] = __builtin_amdgcn_mfma_f32_16x16x32_bf16(wv, pa[0].v,
                                                            acc[ct2][0], 0, 0, 0);
      acc[ct2][1] = __builtin_amdgcn_mfma_f32_16x16x32_bf16(wv, pa[1].v,
                                                            acc[ct2][1], 0, 0, 0);
    }
    // write prefetched chunk into alternate buffers
    if (pf) {
      unsigned short* w1n = (unsigned short*)(smem + (cur ^ 1) * FA_W1OFF);
      unsigned short* w2n =
          (unsigned short*)(smem + FA_W2BASE + (cur ^ 1) * FA_W2OFF);
#pragma unroll
      for (int i = 0; i < 4; i++) {
        int fi = t + 256 * i;
        int c = fi >> 4, u8 = (fi & 15) * 8;
        *(uint4*)&w1n[c * FA_WS + u8] = rA[i];
      }
#pragma unroll
      for (int i = 0; i < 4; i++) {
        int fi = t + 256 * i;
        if (fi < 896) {
          int c = fi >> 3, u8 = (fi & 7) * 8;
          *(uint4*)&w2n[c * FA_PS + u8] = rB[i];
        }
      }
    }
    __syncthreads();
  }

  // cross-h reduction: h==1 waves dump partials, h==0 waves add
  float* red = (float*)smem;
  if (h == 1) {
#pragma unroll
    for (int ct2 = 0; ct2 < 7; ct2++)
#pragma unroll
      for (int ct = 0; ct < 2; ct++)
        *(f32x4*)&red[((rh * 14 + ct2 * 2 + ct) * 64 + l) * 4] = acc[ct2][ct];
  }
  __syncthreads();
  if (h == 0) {
#pragma unroll
    for (int ct2 = 0; ct2 < 7; ct2++)
#pragma unroll
      for (int ct = 0; ct < 2; ct++)
        acc[ct2][ct] += *(f32x4*)&red[((rh * 14 + ct2 * 2 + ct) * 64 + l) * 4];

    // fused masked softmax; lane holds row 32rh+16ct+lr, cols 16ct2+4lg+r
#pragma unroll
    for (int ct = 0; ct < 2; ct++) {
      int xrow = row0 + 32 * rh + 16 * ct + lr;
      float v[7][4];
      float m = 0.0f;  // reference max includes masked zeros
#pragma unroll
      for (int ct2 = 0; ct2 < 7; ct2++) {
        int col0 = 16 * ct2 + 4 * lg;
        if (col0 < KPG) {
          float4 b2 = *(const float4*)(b2p + g * KPG + col0);
          v[ct2][0] = frelu(acc[ct2][ct][0] + b2.x);
          v[ct2][1] = frelu(acc[ct2][ct][1] + b2.y);
          v[ct2][2] = frelu(acc[ct2][ct][2] + b2.z);
          v[ct2][3] = frelu(acc[ct2][ct][3] + b2.w);
          m = fmaxf(m, fmaxf(fmaxf(v[ct2][0], v[ct2][1]),
                             fmaxf(v[ct2][2], v[ct2][3])));
        }
      }
      m = fmaxf(m, __shfl_xor(m, 16, 64));
      m = fmaxf(m, __shfl_xor(m, 32, 64));
      float s = 0.0f;
#pragma unroll
      for (int ct2 = 0; ct2 < 7; ct2++) {
        int col0 = 16 * ct2 + 4 * lg;
        if (col0 < KPG) {
          v[ct2][0] = expf(v[ct2][0] - m);
          v[ct2][1] = expf(v[ct2][1] - m);
          v[ct2][2] = expf(v[ct2][2] - m);
          v[ct2][3] = expf(v[ct2][3] - m);
          s += (v[ct2][0] + v[ct2][1]) + (v[ct2][2] + v[ct2][3]);
        }
      }
      s += __shfl_xor(s, 16, 64);
      s += __shfl_xor(s, 32, 64);
      float denom = s + (float)(K_ASSIGN - KPG) * expf(-m);
      float scale = 1.0f / (s + 1e-13f * denom);
      if (xrow < NPG) {
#pragma unroll
        for (int ct2 = 0; ct2 < 7; ct2++) {
          int col0 = 16 * ct2 + 4 * lg;
          if (col0 < KPG) {
            ushort4 pk;
            pk.x = f2bf(v[ct2][0] * scale);
            pk.y = f2bf(v[ct2][1] * scale);
            pk.z = f2bf(v[ct2][2] * scale);
            pk.w = f2bf(v[ct2][3] * scale);
            *(ushort4*)(assign_bf + ((size_t)g * NPG + xrow) * KPG + col0) = pk;
          }
        }
      }
    }
  }
}

// ---------------------------------------------------------------------------
// tmp_bf[n] = sum_{e->n} assign_bf[src_e] (100-wide). One wave/node, 50 lanes.
// ---------------------------------------------------------------------------
__global__ __launch_bounds__(256) void tmp_gather(
    const int* __restrict__ rowstart, const int* __restrict__ bucket,
    const unsigned short* __restrict__ assign_bf, unsigned short* __restrict__ tmp_bf) {
  int n = blockIdx.x * 4 + (threadIdx.x >> 6);
  int lane = threadIdx.x & 63;
  if (lane >= 50) return;
  int rs = rowstart[n], re = rowstart[n + 1];
  const unsigned* ab = (const unsigned*)assign_bf;
  float ax = 0.f, ay = 0.f;
  int e = rs;
  for (; e + 4 <= re; e += 4) {
    unsigned v0 = ab[(size_t)bucket[e] * 50 + lane];
    unsigned v1 = ab[(size_t)bucket[e + 1] * 50 + lane];
    unsigned v2 = ab[(size_t)bucket[e + 2] * 50 + lane];
    unsigned v3 = ab[(size_t)bucket[e + 3] * 50 + lane];
    ax += (bfLO(v0) + bfLO(v1)) + (bfLO(v2) + bfLO(v3));
    ay += (bfHI(v0) + bfHI(v1)) + (bfHI(v2) + bfHI(v3));
  }
  for (; e < re; e++) {
    unsigned v = ab[(size_t)bucket[e] * 50 + lane];
    ax += bfLO(v);
    ay += bfHI(v);
  }
  unsigned o = ((unsigned)f2bf(ay) << 16) | f2bf(ax);
  ((unsigned*)tmp_bf)[(size_t)n * 50 + lane] = o;
}

// ---------------------------------------------------------------------------
// pool (blocks 0..255) + adj (blocks 256..511) in one launch.
// ---------------------------------------------------------------------------
__global__ __launch_bounds__(256) void pool_adj(
    const unsigned short* __restrict__ assign_bf,
    const unsigned short* __restrict__ feat_bf,
    const unsigned short* __restrict__ tmp_bf,
    float* __restrict__ out_adj, float* __restrict__ out_hpool) {
  __shared__ float as[25][101];
  __shared__ float bs[25][129];
  bool is_pool = blockIdx.x < 256;
  int bb = is_pool ? blockIdx.x : blockIdx.x - 256;
  int g = bb >> 4, ch = bb & 15;
  int nbase0 = g * NPG + ch * 125;
  int t = threadIdx.x;
  int a = t >> 4, b = t & 15;
  float accP[7][8] = {};
  float accA[7][7] = {};
  const unsigned* au = (const unsigned*)assign_bf;
  const unsigned* fu = (const unsigned*)feat_bf;
  const unsigned* tu = (const unsigned*)tmp_bf;
  for (int tile = 0; tile < 5; tile++) {
    int nb = nbase0 + tile * 25;
    __syncthreads();
#pragma unroll
    for (int i = 0; i < 5; i++) {
      int idx = t + i * 256;
      if (idx < 1250) {
        int r = idx / 50, cu = idx % 50;
        unsigned v = au[(size_t)(nb + r) * 50 + cu];
        as[r][cu * 2] = bfLO(v);
        as[r][cu * 2 + 1] = bfHI(v);
      }
    }
    if (is_pool) {
#pragma unroll
      for (int i = 0; i < 7; i++) {
        int idx = t + i * 256;
        if (idx < 1600) {
          int r = idx >> 6, cu = idx & 63;
          unsigned v = fu[(size_t)(nb + r) * 64 + cu];
          bs[r][cu * 2] = bfLO(v);
          bs[r][cu * 2 + 1] = bfHI(v);
        }
      }
    } else {
#pragma unroll
      for (int i = 0; i < 5; i++) {
        int idx = t + i * 256;
        if (idx < 1250) {
          int r = idx / 50, cu = idx % 50;
          unsigned v = tu[(size_t)(nb + r) * 50 + cu];
          bs[r][cu * 2] = bfLO(v);
          bs[r][cu * 2 + 1] = bfHI(v);
        }
      }
    }
    __syncthreads();
    if (is_pool) {
      for (int n = 0; n < 25; n++) {
        float av[7], fv[8];
#pragma unroll
        for (int i = 0; i < 7; i++) {
          int k1 = a + 16 * i;
          av[i] = (k1 < KPG) ? as[n][k1] : 0.0f;
        }
#pragma unroll
        for (int j = 0; j < 8; j++) fv[j] = bs[n][b + 16 * j];
#pragma unroll
        for (int i = 0; i < 7; i++)
#pragma unroll
          for (int j = 0; j < 8; j++) accP[i][j] += av[i] * fv[j];
      }
    } else {
      for (int n = 0; n < 25; n++) {
        float av[7], tv[7];
#pragma unroll
        for (int i = 0; i < 7; i++) {
          int k1 = a + 16 * i;
          av[i] = (k1 < KPG) ? as[n][k1] : 0.0f;
        }
#pragma unroll
        for (int j = 0; j < 7; j++) {
          int k2 = b + 16 * j;
          tv[j] = (k2 < KPG) ? bs[n][k2] : 0.0f;
        }
#pragma unroll
        for (int i = 0; i < 7; i++)
#pragma unroll
          for (int j = 0; j < 7; j++) accA[i][j] += av[i] * tv[j];
      }
    }
  }
  if (is_pool) {
    for (int i = 0; i < 7; i++) {
      int k1 = a + 16 * i;
      if (k1 < KPG)
        for (int j = 0; j < 8; j++)
          atomicAdd(out_hpool + (size_t)(g * KPG + k1) * 128 + b + 16 * j,
                    accP[i][j]);
    }
  } else {
    for (int i = 0; i < 7; i++) {
      int k1 = a + 16 * i;
      if (k1 >= KPG) continue;
      for (int j = 0; j < 7; j++) {
        int k2 = b + 16 * j;
        if (k2 < KPG)
          atomicAdd(out_adj + (size_t)(g * KPG + k1) * K_ASSIGN + g * KPG + k2,
                    accA[i][j]);
      }
    }
  }
}

extern "C" void kernel_launch(void* const* d_in, const int* in_sizes, int n_in,
                              void* d_out, int out_size, void* d_ws,
                              size_t ws_size, hipStream_t stream) {
  (void)in_sizes; (void)n_in; (void)ws_size;
  const float* h   = (const float*)d_in[0];
  const int*   src = (const int*)d_in[1];
  const int*   dst = (const int*)d_in[2];
  const float* W1f = (const float*)d_in[3];
  const float* b1f = (const float*)d_in[4];
  const float* W2f = (const float*)d_in[5];
  const float* b2f = (const float*)d_in[6];
  const float* W1p = (const float*)d_in[7];
  const float* b1p = (const float*)d_in[8];
  const float* W2p = (const float*)d_in[9];
  const float* b2p = (const float*)d_in[10];

  float* out_adj   = (float*)d_out;
  float* out_hpool = out_adj + (size_t)K_ASSIGN * K_ASSIGN;

  char* ws = (char*)d_ws;
  int* deg_cnt  = (int*)(ws + 0);            //   128,000
  int* rowstart = (int*)(ws + 128000);       //   128,032
  int* cursor   = (int*)(ws + 256032);       //   128,000
  int* bucket   = (int*)(ws + 384032);       // 2,048,000
  unsigned short* h_bf      = (unsigned short*)(ws + 2432032);   // 8,192,000
  unsigned short* x_bf      = (unsigned short*)(ws + 10624032);  // 8,192,000
  unsigned short* feat_bf   = (unsigned short*)(ws + 18816032);  // 8,192,000
  unsigned short* assign_bf = (unsigned short*)(ws + 27008032);  // 6,400,000
  unsigned short* tmp_bf    = (unsigned short*)(ws + 33408032);  // 6,400,000
  unsigned short* w1f_t     = (unsigned short*)(ws + 39808032);  //    32,768
  unsigned short* w2f_t     = (unsigned short*)(ws + 39840800);  //    32,768
  unsigned short* w1p_t     = (unsigned short*)(ws + 39873568);  //   409,600
  unsigned short* w2p_t     = (unsigned short*)(ws + 40283168);  // 5,120,000

  hipMemsetAsync(deg_cnt, 0, 128000, stream);
  hipMemsetAsync(cursor, 0, 128000, stream);
  hipMemsetAsync(d_out, 0, (size_t)out_size * sizeof(float), stream);

  // CSR build (by dst)
  edge_hist<<<N_EDGES / 256, 256, 0, stream>>>(dst, deg_cnt);
  scan_counts<<<1, 256, 0, stream>>>(deg_cnt, rowstart);
  edge_fill<<<N_EDGES / 256, 256, 0, stream>>>(src, dst, rowstart, cursor, bucket);

  // conversions / transposes
  h_to_bf<<<N_NODES * 128 / 4 / 256, 256, 0, stream>>>(h, h_bf);
  transpose_all<<<16 + 16 + 200 + 2500, 256, 0, stream>>>(
      W1f, W2f, W1p, W2p, w1f_t, w2f_t, w1p_t, w2p_t);

  // aggregation (gather) -> x in bf16
  gin_gather<<<N_NODES / 4, 256, 0, stream>>>(rowstart, bucket, h, h_bf, x_bf);

  // feat path: one fused kernel
  feat_fused<<<N_NODES / 128, 512, 0, stream>>>(x_bf, w1f_t, b1f, w2f_t, b2f, feat_bf);

  // assign path: fused 2-layer MFMA + masked softmax, bf16 out
  fused_assign_sm<<<512, 256, 0, stream>>>(x_bf, w1p_t, b1p, w2p_t, b2p, assign_bf);

  // adj @ assign via gather
  tmp_gather<<<N_NODES / 4, 256, 0, stream>>>(rowstart, bucket, assign_bf, tmp_bf);

  // outputs
  pool_adj<<<512, 256, 0, stream>>>(assign_bf, feat_bf, tmp_bf, out_adj, out_hpool);
}

// Round 7
// 240.684 us; speedup vs baseline: 9.9714x; 1.1082x over previous
//
#include <hip/hip_runtime.h>

#define N_NODES 32000
#define NPG     2000
#define NGRAPH  16
#define K_ASSIGN 1600
#define KPG     100
#define D_FEAT  128
#define N_EDGES 512000

typedef float f32x4 __attribute__((ext_vector_type(4)));
typedef __bf16 bf16x8 __attribute__((ext_vector_type(8)));

union FragU { unsigned u[4]; bf16x8 v; };

__device__ __forceinline__ float frelu(float v) { return fmaxf(v, 0.0f); }

__device__ __forceinline__ unsigned short f2bf(float f) {
  unsigned u = __float_as_uint(f);
  u += 0x7FFFu + ((u >> 16) & 1u);
  return (unsigned short)(u >> 16);
}
__device__ __forceinline__ float bfLO(unsigned v) { return __uint_as_float(v << 16); }
__device__ __forceinline__ float bfHI(unsigned v) { return __uint_as_float(v & 0xFFFF0000u); }

// ---------------------------------------------------------------------------
// CSR build
// ---------------------------------------------------------------------------
__global__ __launch_bounds__(256) void edge_hist(
    const int* __restrict__ dst, int* __restrict__ cnt) {
  int e = blockIdx.x * 256 + threadIdx.x;
  if (e < N_EDGES) atomicAdd(&cnt[dst[e]], 1);
}

__global__ __launch_bounds__(256) void scan_counts(
    const int* __restrict__ cnt, int* __restrict__ rowstart) {
  __shared__ int sums[256];
  int t = threadIdx.x;
  int base = t * 125;
  int s = 0;
  for (int i = 0; i < 125; i++) s += cnt[base + i];
  sums[t] = s;
  __syncthreads();
  for (int off = 1; off < 256; off <<= 1) {
    int v = (t >= off) ? sums[t - off] : 0;
    __syncthreads();
    sums[t] += v;
    __syncthreads();
  }
  int run = (t == 0) ? 0 : sums[t - 1];
  for (int i = 0; i < 125; i++) {
    rowstart[base + i] = run;
    run += cnt[base + i];
  }
  if (t == 255) rowstart[32000] = run;
}

__global__ __launch_bounds__(256) void edge_fill(
    const int* __restrict__ src, const int* __restrict__ dst,
    const int* __restrict__ rowstart, int* __restrict__ cursor,
    int* __restrict__ bucket) {
  int e = blockIdx.x * 256 + threadIdx.x;
  if (e < N_EDGES) {
    int d = dst[e];
    int pos = atomicAdd(&cursor[d], 1);
    bucket[rowstart[d] + pos] = src[e];
  }
}

// ---------------------------------------------------------------------------
// h (f32) -> bf16 copy
// ---------------------------------------------------------------------------
__global__ __launch_bounds__(256) void h_to_bf(
    const float* __restrict__ h, unsigned short* __restrict__ hb) {
  int i = blockIdx.x * 256 + threadIdx.x;  // float4 index
  float4 v = ((const float4*)h)[i];
  ushort4 o;
  o.x = f2bf(v.x); o.y = f2bf(v.y); o.z = f2bf(v.z); o.w = f2bf(v.w);
  ((ushort4*)hb)[i] = o;
}

// ---------------------------------------------------------------------------
// Gather aggregation + compute_x: x_bf[n] = bf16(h[n] + mean h_bf[src])
// ---------------------------------------------------------------------------
__global__ __launch_bounds__(256) void gin_gather(
    const int* __restrict__ rowstart, const int* __restrict__ bucket,
    const float* __restrict__ h, const unsigned short* __restrict__ h_bf,
    unsigned short* __restrict__ x_bf) {
  int n = blockIdx.x * 4 + (threadIdx.x >> 6);
  int lane = threadIdx.x & 63;
  int rs = rowstart[n], re = rowstart[n + 1];
  const unsigned* hb = (const unsigned*)h_bf;
  float ax = 0.f, ay = 0.f;
  int e = rs;
  for (; e + 4 <= re; e += 4) {
    unsigned v0 = hb[(size_t)bucket[e] * 64 + lane];
    unsigned v1 = hb[(size_t)bucket[e + 1] * 64 + lane];
    unsigned v2 = hb[(size_t)bucket[e + 2] * 64 + lane];
    unsigned v3 = hb[(size_t)bucket[e + 3] * 64 + lane];
    ax += (bfLO(v0) + bfLO(v1)) + (bfLO(v2) + bfLO(v3));
    ay += (bfHI(v0) + bfHI(v1)) + (bfHI(v2) + bfHI(v3));
  }
  for (; e < re; e++) {
    unsigned v = hb[(size_t)bucket[e] * 64 + lane];
    ax += bfLO(v);
    ay += bfHI(v);
  }
  float invd = 1.0f / fmaxf((float)(re - rs), 1.0f);
  float2 hv = ((const float2*)h)[(size_t)n * 64 + lane];
  unsigned o = ((unsigned)f2bf(hv.y + ay * invd) << 16) | f2bf(hv.x + ax * invd);
  ((unsigned*)x_bf)[(size_t)n * 64 + lane] = o;
}

// ---------------------------------------------------------------------------
// All weight transposes (f32 [R][C] -> bf16 [C][R]) in one launch.
// ---------------------------------------------------------------------------
__global__ __launch_bounds__(256) void transpose_all(
    const float* __restrict__ W1f, const float* __restrict__ W2f,
    const float* __restrict__ W1p, const float* __restrict__ W2p,
    unsigned short* __restrict__ o1, unsigned short* __restrict__ o2,
    unsigned short* __restrict__ o3, unsigned short* __restrict__ o4) {
  __shared__ float tile[32][33];
  int b = blockIdx.x;
  const float* in;
  unsigned short* out;
  int R, C, rb;
  if (b < 16)       { in = W1f; out = o1; R = 128;  C = 128;  rb = b; }
  else if (b < 32)  { in = W2f; out = o2; R = 128;  C = 128;  rb = b - 16; }
  else if (b < 232) { in = W1p; out = o3; R = 128;  C = 1600; rb = b - 32; }
  else              { in = W2p; out = o4; R = 1600; C = 1600; rb = b - 232; }
  int ct = C >> 5;
  int bc = rb % ct, br = rb / ct;
  int r0 = br * 32, c0 = bc * 32;
  int t = threadIdx.x;
#pragma unroll
  for (int i = 0; i < 4; i++) {
    int r = (t >> 5) + i * 8, c = t & 31;
    tile[r][c] = in[(size_t)(r0 + r) * C + c0 + c];
  }
  __syncthreads();
#pragma unroll
  for (int i = 0; i < 4; i++) {
    int c = (t >> 5) + i * 8, r = t & 31;
    out[(size_t)(c0 + c) * R + r0 + r] = f2bf(tile[r][c]);
  }
}

// ---------------------------------------------------------------------------
// Fused feat path: feat = relu(relu(x@W1f+b1f)@W2f+b2f), bf16 out.
// ---------------------------------------------------------------------------
#define FF_STR 136
__global__ __launch_bounds__(512) void feat_fused(
    const unsigned short* __restrict__ x_bf,
    const unsigned short* __restrict__ w1t, const float* __restrict__ b1f,
    const unsigned short* __restrict__ w2t, const float* __restrict__ b2f,
    unsigned short* __restrict__ feat_bf) {
  __shared__ __align__(16) unsigned char smem[2 * 34816];
  unsigned short* xa = (unsigned short*)smem;            // xt, then x1
  unsigned short* ws = (unsigned short*)(smem + 34816);  // W1, then W2
  int t = threadIdx.x;
  size_t base = (size_t)blockIdx.x * 128;

#pragma unroll
  for (int i = 0; i < 4; i++) {
    int fi = t + 512 * i;
    int r = fi >> 4, u8 = (fi & 15) * 8;
    *(uint4*)&xa[r * FF_STR + u8] = *(const uint4*)(x_bf + (base + r) * 128 + u8);
    *(uint4*)&ws[r * FF_STR + u8] = *(const uint4*)(w1t + (size_t)r * 128 + u8);
  }
  __syncthreads();

  int w = t >> 6, l = t & 63, lr = l & 15, lg = l >> 4;
  int myrow = 16 * w + lr;
  bf16x8 af[4];
#pragma unroll
  for (int kc = 0; kc < 4; kc++)
    af[kc] = *(bf16x8*)&xa[myrow * FF_STR + 32 * kc + 8 * lg];

  // phase 1: x1^T fragments (swapped)
  f32x4 p[8];
#pragma unroll
  for (int ntk = 0; ntk < 8; ntk++) {
    p[ntk] = (f32x4){0.f, 0.f, 0.f, 0.f};
    int c = 16 * ntk + lr;
#pragma unroll
    for (int kc = 0; kc < 4; kc++) {
      bf16x8 wf = *(bf16x8*)&ws[c * FF_STR + 32 * kc + 8 * lg];
      p[ntk] = __builtin_amdgcn_mfma_f32_16x16x32_bf16(wf, af[kc], p[ntk], 0, 0, 0);
    }
  }
  __syncthreads();  // xt + W1 fully read

  // write x1 (bf16) over xt; stage W2 over W1
#pragma unroll
  for (int ntk = 0; ntk < 8; ntk++) {
    int kk0 = 16 * ntk + 4 * lg;
    float4 b1 = *(const float4*)(b1f + kk0);
    ushort4 pk;
    pk.x = f2bf(frelu(p[ntk][0] + b1.x));
    pk.y = f2bf(frelu(p[ntk][1] + b1.y));
    pk.z = f2bf(frelu(p[ntk][2] + b1.z));
    pk.w = f2bf(frelu(p[ntk][3] + b1.w));
    *(ushort4*)&xa[myrow * FF_STR + kk0] = pk;
  }
#pragma unroll
  for (int i = 0; i < 4; i++) {
    int fi = t + 512 * i;
    int r = fi >> 4, u8 = (fi & 15) * 8;
    *(uint4*)&ws[r * FF_STR + u8] = *(const uint4*)(w2t + (size_t)r * 128 + u8);
  }
  __syncthreads();

  // phase 2 (swapped): feat
  bf16x8 a2[4];
#pragma unroll
  for (int kc = 0; kc < 4; kc++)
    a2[kc] = *(bf16x8*)&xa[myrow * FF_STR + 32 * kc + 8 * lg];
#pragma unroll
  for (int nt = 0; nt < 8; nt++) {
    f32x4 q = (f32x4){0.f, 0.f, 0.f, 0.f};
    int c = 16 * nt + lr;
#pragma unroll
    for (int kc = 0; kc < 4; kc++) {
      bf16x8 wf = *(bf16x8*)&ws[c * FF_STR + 32 * kc + 8 * lg];
      q = __builtin_amdgcn_mfma_f32_16x16x32_bf16(wf, a2[kc], q, 0, 0, 0);
    }
    int c0 = 16 * nt + 4 * lg;
    float4 b2 = *(const float4*)(b2f + c0);
    ushort4 pk;
    pk.x = f2bf(frelu(q[0] + b2.x));
    pk.y = f2bf(frelu(q[1] + b2.y));
    pk.z = f2bf(frelu(q[2] + b2.z));
    pk.w = f2bf(frelu(q[3] + b2.w));
    *(ushort4*)&feat_bf[(base + myrow) * 128 + c0] = pk;
  }
}

// ---------------------------------------------------------------------------
// Fused assign path + softmax. 128 rows/block (256 blocks), 8 waves.
// Wave (rh,h): rows 32rh..+31 (rh 0..3), kk-half 32h..+31 (h 0..1).
// Halving the block count halves the per-block-amortized W1p/W2p streaming
// (374 MB -> 187 MB of L2/L3 traffic).
// ---------------------------------------------------------------------------
#define FA_WS 136  // 128+8 ushorts (pad rotates banks)
#define FA_PS 72   // 64+8 ushorts
#define FA_W1OFF 17408
#define FA_W2BASE 34816
#define FA_W2OFF 16128
__global__ __launch_bounds__(512) void fused_assign_sm(
    const unsigned short* __restrict__ x_bf, const unsigned short* __restrict__ w1t,
    const float* __restrict__ b1p, const unsigned short* __restrict__ w2t,
    const float* __restrict__ b2p, unsigned short* __restrict__ assign_bf) {
  // [0,34816) xt (128x136) overlaying w1 buf0+buf1;
  // [34816,50944) w2 buf0; [50944,67072) w2 buf1.
  // End reduction reuses [0, 57344).
  __shared__ __align__(16) unsigned char smem[67072];
  unsigned short* xt = (unsigned short*)smem;

  int t = threadIdx.x;
  int g = blockIdx.x >> 4;
  int row0 = (blockIdx.x & 15) << 7;
  int n0 = g * NPG + row0;

  // stage x tile (rows 0..127), zero-fill past NPG
#pragma unroll
  for (int i = 0; i < 4; i++) {
    int fi = t + 512 * i;
    int r = fi >> 4, u8 = (fi & 15) * 8;
    uint4 v = make_uint4(0, 0, 0, 0);
    if (row0 + r < NPG) v = *(const uint4*)(x_bf + (size_t)(n0 + r) * 128 + u8);
    *(uint4*)&xt[r * FA_WS + u8] = v;
  }
  __syncthreads();

  int w = t >> 6, l = t & 63, lr = l & 15, lg = l >> 4;
  int rh = w >> 1, h = w & 1;

  // resident x fragments: rows 32rh+16ct+lr, k = 32kc+8lg..+7
  bf16x8 af[2][4];
#pragma unroll
  for (int ct = 0; ct < 2; ct++)
#pragma unroll
    for (int kc = 0; kc < 4; kc++)
      af[ct][kc] =
          *(bf16x8*)&xt[(32 * rh + 16 * ct + lr) * FA_WS + 32 * kc + 8 * lg];
  __syncthreads();  // xt region becomes w1 buffers

  // stage chunk 0
  {
    unsigned short* w1s = (unsigned short*)smem;
    unsigned short* w2s = (unsigned short*)(smem + FA_W2BASE);
#pragma unroll
    for (int i = 0; i < 2; i++) {
      int fi = t + 512 * i;
      int c = fi >> 4, u8 = (fi & 15) * 8;
      *(uint4*)&w1s[c * FA_WS + u8] = *(const uint4*)(w1t + (size_t)c * 128 + u8);
    }
#pragma unroll
    for (int i = 0; i < 2; i++) {
      int fi = t + 512 * i;
      if (fi < 896) {
        int c = fi >> 3, u8 = (fi & 7) * 8;
        uint4 v = make_uint4(0, 0, 0, 0);
        if (c < KPG)
          v = *(const uint4*)(w2t + (size_t)(g * KPG + c) * K_ASSIGN + u8);
        *(uint4*)&w2s[c * FA_PS + u8] = v;
      }
    }
  }
  __syncthreads();

  f32x4 acc[7][2];
#pragma unroll
  for (int i = 0; i < 7; i++) {
    acc[i][0] = (f32x4){0.f, 0.f, 0.f, 0.f};
    acc[i][1] = (f32x4){0.f, 0.f, 0.f, 0.f};
  }

  for (int cch = 0; cch < 25; cch++) {
    int cur = cch & 1;
    int k0 = cch * 64;
    const unsigned short* w1c = (const unsigned short*)(smem + cur * FA_W1OFF);
    const unsigned short* w2c =
        (const unsigned short*)(smem + FA_W2BASE + cur * FA_W2OFF);
    bool pf = (cch < 24);
    uint4 rA[2], rB[2];
    if (pf) {  // issue next-chunk loads early (hide under MFMA phases)
      int k1 = k0 + 64;
#pragma unroll
      for (int i = 0; i < 2; i++) {
        int fi = t + 512 * i;
        int c = fi >> 4, u8 = (fi & 15) * 8;
        rA[i] = *(const uint4*)(w1t + (size_t)(k1 + c) * 128 + u8);
      }
#pragma unroll
      for (int i = 0; i < 2; i++) {
        int fi = t + 512 * i;
        rB[i] = make_uint4(0, 0, 0, 0);
        if (fi < 896) {
          int c = fi >> 3, u8 = (fi & 7) * 8;
          if (c < KPG)
            rB[i] = *(const uint4*)(w2t + (size_t)(g * KPG + c) * K_ASSIGN +
                                    k1 + u8);
        }
      }
    }

    // phase 1 (swapped): p[nt2][ct] = P^T frag, lane holds
    // P[xrow=32rh+16ct+lr][kk = 16*(2h+nt2) + 4lg + reg]
    f32x4 p[2][2];
#pragma unroll
    for (int nt2 = 0; nt2 < 2; nt2++) {
      p[nt2][0] = (f32x4){0.f, 0.f, 0.f, 0.f};
      p[nt2][1] = (f32x4){0.f, 0.f, 0.f, 0.f};
      int nt = 2 * h + nt2;
#pragma unroll
      for (int kc = 0; kc < 4; kc++) {
        bf16x8 wf = *(bf16x8*)&w1c[(16 * nt + lr) * FA_WS + 32 * kc + 8 * lg];
        p[nt2][0] = __builtin_amdgcn_mfma_f32_16x16x32_bf16(wf, af[0][kc],
                                                            p[nt2][0], 0, 0, 0);
        p[nt2][1] = __builtin_amdgcn_mfma_f32_16x16x32_bf16(wf, af[1][kc],
                                                            p[nt2][1], 0, 0, 0);
      }
    }
    // bias + relu + pack to bf16 pairs
    unsigned q[2][2][2];
#pragma unroll
    for (int nt2 = 0; nt2 < 2; nt2++) {
      int kkb = k0 + 16 * (2 * h + nt2) + 4 * lg;
      float4 b1 = *(const float4*)(b1p + kkb);
#pragma unroll
      for (int ct = 0; ct < 2; ct++) {
        float r0 = frelu(p[nt2][ct][0] + b1.x);
        float r1 = frelu(p[nt2][ct][1] + b1.y);
        float r2 = frelu(p[nt2][ct][2] + b1.z);
        float r3 = frelu(p[nt2][ct][3] + b1.w);
        q[nt2][ct][0] = ((unsigned)f2bf(r1) << 16) | f2bf(r0);
        q[nt2][ct][1] = ((unsigned)f2bf(r3) << 16) | f2bf(r2);
      }
    }
    // regroup to B-frag layout via shfl (within-wave)
    int sA = lr + 32 * (lg & 1);
    int sB = sA + 16;
    bool hi = (lg >= 2);
    FragU pa[2];
#pragma unroll
    for (int ct = 0; ct < 2; ct++) {
      unsigned a0 = (unsigned)__shfl((int)q[0][ct][0], sA, 64);
      unsigned b0 = (unsigned)__shfl((int)q[1][ct][0], sA, 64);
      unsigned a1 = (unsigned)__shfl((int)q[0][ct][1], sA, 64);
      unsigned b1u = (unsigned)__shfl((int)q[1][ct][1], sA, 64);
      unsigned a2 = (unsigned)__shfl((int)q[0][ct][0], sB, 64);
      unsigned b2u = (unsigned)__shfl((int)q[1][ct][0], sB, 64);
      unsigned a3 = (unsigned)__shfl((int)q[0][ct][1], sB, 64);
      unsigned b3u = (unsigned)__shfl((int)q[1][ct][1], sB, 64);
      pa[ct].u[0] = hi ? b0 : a0;
      pa[ct].u[1] = hi ? b1u : a1;
      pa[ct].u[2] = hi ? b2u : a2;
      pa[ct].u[3] = hi ? b3u : a3;
    }
    // phase 2: acc[ct2][ct] += W2^T-frag @ P-frag over klocal 0..31
#pragma unroll
    for (int ct2 = 0; ct2 < 7; ct2++) {
      bf16x8 wv = *(bf16x8*)&w2c[(16 * ct2 + lr) * FA_PS + 32 * h + 8 * lg];
      acc[ct2][0] = __builtin_amdgcn_mfma_f32_16x16x32_bf16(wv, pa[0].v,
                                                            acc[ct2][0], 0, 0, 0);
      acc[ct2][1] = __builtin_amdgcn_mfma_f32_16x16x32_bf16(wv, pa[1].v,
                                                            acc[ct2][1], 0, 0, 0);
    }
    // write prefetched chunk into alternate buffers
    if (pf) {
      unsigned short* w1n = (unsigned short*)(smem + (cur ^ 1) * FA_W1OFF);
      unsigned short* w2n =
          (unsigned short*)(smem + FA_W2BASE + (cur ^ 1) * FA_W2OFF);
#pragma unroll
      for (int i = 0; i < 2; i++) {
        int fi = t + 512 * i;
        int c = fi >> 4, u8 = (fi & 15) * 8;
        *(uint4*)&w1n[c * FA_WS + u8] = rA[i];
      }
#pragma unroll
      for (int i = 0; i < 2; i++) {
        int fi = t + 512 * i;
        if (fi < 896) {
          int c = fi >> 3, u8 = (fi & 7) * 8;
          *(uint4*)&w2n[c * FA_PS + u8] = rB[i];
        }
      }
    }
    __syncthreads();
  }

  // cross-h reduction: h==1 waves dump partials, h==0 waves add
  float* red = (float*)smem;
  if (h == 1) {
#pragma unroll
    for (int ct2 = 0; ct2 < 7; ct2++)
#pragma unroll
      for (int ct = 0; ct < 2; ct++)
        *(f32x4*)&red[((rh * 14 + ct2 * 2 + ct) * 64 + l) * 4] = acc[ct2][ct];
  }
  __syncthreads();
  if (h == 0) {
#pragma unroll
    for (int ct2 = 0; ct2 < 7; ct2++)
#pragma unroll
      for (int ct = 0; ct < 2; ct++)
        acc[ct2][ct] += *(f32x4*)&red[((rh * 14 + ct2 * 2 + ct) * 64 + l) * 4];

    // fused masked softmax; lane holds row 32rh+16ct+lr, cols 16ct2+4lg+r
#pragma unroll
    for (int ct = 0; ct < 2; ct++) {
      int xrow = row0 + 32 * rh + 16 * ct + lr;
      float v[7][4];
      float m = 0.0f;  // reference max includes masked zeros
#pragma unroll
      for (int ct2 = 0; ct2 < 7; ct2++) {
        int col0 = 16 * ct2 + 4 * lg;
        if (col0 < KPG) {
          float4 b2 = *(const float4*)(b2p + g * KPG + col0);
          v[ct2][0] = frelu(acc[ct2][ct][0] + b2.x);
          v[ct2][1] = frelu(acc[ct2][ct][1] + b2.y);
          v[ct2][2] = frelu(acc[ct2][ct][2] + b2.z);
          v[ct2][3] = frelu(acc[ct2][ct][3] + b2.w);
          m = fmaxf(m, fmaxf(fmaxf(v[ct2][0], v[ct2][1]),
                             fmaxf(v[ct2][2], v[ct2][3])));
        }
      }
      m = fmaxf(m, __shfl_xor(m, 16, 64));
      m = fmaxf(m, __shfl_xor(m, 32, 64));
      float s = 0.0f;
#pragma unroll
      for (int ct2 = 0; ct2 < 7; ct2++) {
        int col0 = 16 * ct2 + 4 * lg;
        if (col0 < KPG) {
          v[ct2][0] = expf(v[ct2][0] - m);
          v[ct2][1] = expf(v[ct2][1] - m);
          v[ct2][2] = expf(v[ct2][2] - m);
          v[ct2][3] = expf(v[ct2][3] - m);
          s += (v[ct2][0] + v[ct2][1]) + (v[ct2][2] + v[ct2][3]);
        }
      }
      s += __shfl_xor(s, 16, 64);
      s += __shfl_xor(s, 32, 64);
      float denom = s + (float)(K_ASSIGN - KPG) * expf(-m);
      float scale = 1.0f / (s + 1e-13f * denom);
      if (xrow < NPG) {
#pragma unroll
        for (int ct2 = 0; ct2 < 7; ct2++) {
          int col0 = 16 * ct2 + 4 * lg;
          if (col0 < KPG) {
            ushort4 pk;
            pk.x = f2bf(v[ct2][0] * scale);
            pk.y = f2bf(v[ct2][1] * scale);
            pk.z = f2bf(v[ct2][2] * scale);
            pk.w = f2bf(v[ct2][3] * scale);
            *(ushort4*)(assign_bf + ((size_t)g * NPG + xrow) * KPG + col0) = pk;
          }
        }
      }
    }
  }
}

// ---------------------------------------------------------------------------
// tmp_bf[n] = sum_{e->n} assign_bf[src_e] (100-wide). One wave/node, 50 lanes.
// ---------------------------------------------------------------------------
__global__ __launch_bounds__(256) void tmp_gather(
    const int* __restrict__ rowstart, const int* __restrict__ bucket,
    const unsigned short* __restrict__ assign_bf, unsigned short* __restrict__ tmp_bf) {
  int n = blockIdx.x * 4 + (threadIdx.x >> 6);
  int lane = threadIdx.x & 63;
  if (lane >= 50) return;
  int rs = rowstart[n], re = rowstart[n + 1];
  const unsigned* ab = (const unsigned*)assign_bf;
  float ax = 0.f, ay = 0.f;
  int e = rs;
  for (; e + 4 <= re; e += 4) {
    unsigned v0 = ab[(size_t)bucket[e] * 50 + lane];
    unsigned v1 = ab[(size_t)bucket[e + 1] * 50 + lane];
    unsigned v2 = ab[(size_t)bucket[e + 2] * 50 + lane];
    unsigned v3 = ab[(size_t)bucket[e + 3] * 50 + lane];
    ax += (bfLO(v0) + bfLO(v1)) + (bfLO(v2) + bfLO(v3));
    ay += (bfHI(v0) + bfHI(v1)) + (bfHI(v2) + bfHI(v3));
  }
  for (; e < re; e++) {
    unsigned v = ab[(size_t)bucket[e] * 50 + lane];
    ax += bfLO(v);
    ay += bfHI(v);
  }
  unsigned o = ((unsigned)f2bf(ay) << 16) | f2bf(ax);
  ((unsigned*)tmp_bf)[(size_t)n * 50 + lane] = o;
}

// ---------------------------------------------------------------------------
// pool (blocks 0..255) + adj (blocks 256..511), MFMA over K=n.
// Staging does an in-LDS transpose: operands are n-major in memory; MFMA
// A/B frags need [m][n] / [col][n] tiles. Stride 72 keeps b128 frag reads
// 2-way-conflict free (same geometry as FA_PS).
// pool: h_pool[g*100+m][d] = sum_n assign[n][m]*feat[n][d]  (M=100,N=128)
// adj : adj[g*100+m][g*100+k2] = sum_n assign[n][m]*tmp[n][k2] (M=100,N=100)
// 16 n-chunks of 128 per graph; f32 atomicAdd epilogue.
// ---------------------------------------------------------------------------
#define PA_STR 72
#define PA_CH 16
#define PA_CHN 128
__global__ __launch_bounds__(256) void pool_adj_mfma(
    const unsigned short* __restrict__ assign_bf,
    const unsigned short* __restrict__ feat_bf,
    const unsigned short* __restrict__ tmp_bf,
    float* __restrict__ out_adj, float* __restrict__ out_hpool) {
  __shared__ __align__(16) unsigned short as[112 * PA_STR];  // 16128 B
  __shared__ __align__(16) unsigned short bs[128 * PA_STR];  // 18432 B
  bool is_pool = blockIdx.x < NGRAPH * PA_CH;
  int bb = is_pool ? blockIdx.x : blockIdx.x - NGRAPH * PA_CH;
  int g = bb >> 4, ch = bb & 15;
  int nbase = ch * PA_CHN;
  int lim = NPG - nbase;
  if (lim > PA_CHN) lim = PA_CHN;  // 128, except last chunk: 80
  int t = threadIdx.x;
  int w = t >> 6, l = t & 63, lr = l & 15, lg = l >> 4;
  const unsigned* au = (const unsigned*)assign_bf;
  const unsigned* fu = (const unsigned*)feat_bf;
  const unsigned* tu = (const unsigned*)tmp_bf;

  // zero pad rows (m >= 100 for as; col-rows >= 100 for bs in adj path)
  for (int i = t; i < 12 * PA_STR; i += 256) as[100 * PA_STR + i] = 0;
  for (int i = t; i < 28 * PA_STR; i += 256) bs[100 * PA_STR + i] = 0;

  f32x4 acc[7][2];
#pragma unroll
  for (int i = 0; i < 7; i++) {
    acc[i][0] = (f32x4){0.f, 0.f, 0.f, 0.f};
    acc[i][1] = (f32x4){0.f, 0.f, 0.f, 0.f};
  }

  for (int kt = 0; kt < 2; kt++) {
    int nt0 = kt * 64;
    __syncthreads();  // prev compute done (and initial zero visible)
    // stage A (transpose): 64 n x 50 k-pairs from assign
#pragma unroll
    for (int i = 0; i < 13; i++) {
      int idx = t + 256 * i;
      if (idx < 3200) {
        int r = idx / 50, cu = idx % 50;
        int nl = nt0 + r;
        unsigned v = 0;
        if (nl < lim) v = au[(size_t)(g * NPG + nbase + nl) * 50 + cu];
        as[(2 * cu) * PA_STR + r] = (unsigned short)(v & 0xFFFFu);
        as[(2 * cu + 1) * PA_STR + r] = (unsigned short)(v >> 16);
      }
    }
    if (is_pool) {  // stage B = feat (64 n x 64 d-pairs)
#pragma unroll
      for (int i = 0; i < 16; i++) {
        int idx = t + 256 * i;
        int r = idx >> 6, cu = idx & 63;
        int nl = nt0 + r;
        unsigned v = 0;
        if (nl < lim) v = fu[(size_t)(g * NPG + nbase + nl) * 64 + cu];
        bs[(2 * cu) * PA_STR + r] = (unsigned short)(v & 0xFFFFu);
        bs[(2 * cu + 1) * PA_STR + r] = (unsigned short)(v >> 16);
      }
    } else {  // stage B = tmp (64 n x 50 k2-pairs)
#pragma unroll
      for (int i = 0; i < 13; i++) {
        int idx = t + 256 * i;
        if (idx < 3200) {
          int r = idx / 50, cu = idx % 50;
          int nl = nt0 + r;
          unsigned v = 0;
          if (nl < lim) v = tu[(size_t)(g * NPG + nbase + nl) * 50 + cu];
          bs[(2 * cu) * PA_STR + r] = (unsigned short)(v & 0xFFFFu);
          bs[(2 * cu + 1) * PA_STR + r] = (unsigned short)(v >> 16);
        }
      }
    }
    __syncthreads();
    // compute: 2 MFMA-K steps of 32 over the 64-n tile
#pragma unroll
    for (int kc = 0; kc < 2; kc++) {
      bf16x8 afr[7];
#pragma unroll
      for (int mt = 0; mt < 7; mt++)
        afr[mt] = *(bf16x8*)&as[(16 * mt + lr) * PA_STR + 32 * kc + 8 * lg];
#pragma unroll
      for (int nt2 = 0; nt2 < 2; nt2++) {
        int nt = 2 * w + nt2;
        bf16x8 bfr = *(bf16x8*)&bs[(16 * nt + lr) * PA_STR + 32 * kc + 8 * lg];
#pragma unroll
        for (int mt = 0; mt < 7; mt++)
          acc[mt][nt2] =
              __builtin_amdgcn_mfma_f32_16x16x32_bf16(afr[mt], bfr, acc[mt][nt2], 0, 0, 0);
      }
    }
  }

  // epilogue: atomic f32 adds; D[row = 16mt+4lg+r][col = 16nt+lr]
  if (is_pool) {
#pragma unroll
    for (int mt = 0; mt < 7; mt++)
#pragma unroll
      for (int nt2 = 0; nt2 < 2; nt2++) {
        int nt = 2 * w + nt2;
#pragma unroll
        for (int r = 0; r < 4; r++) {
          int m = 16 * mt + 4 * lg + r;
          if (m < KPG)
            atomicAdd(out_hpool + ((size_t)g * KPG + m) * 128 + 16 * nt + lr,
                      acc[mt][nt2][r]);
        }
      }
  } else {
#pragma unroll
    for (int mt = 0; mt < 7; mt++)
#pragma unroll
      for (int nt2 = 0; nt2 < 2; nt2++) {
        int nt = 2 * w + nt2;
        if (nt < 7) {
          int k2 = 16 * nt + lr;
          if (k2 < KPG) {
#pragma unroll
            for (int r = 0; r < 4; r++) {
              int m = 16 * mt + 4 * lg + r;
              if (m < KPG)
                atomicAdd(out_adj + ((size_t)g * KPG + m) * K_ASSIGN + g * KPG + k2,
                          acc[mt][nt2][r]);
            }
          }
        }
      }
  }
}

extern "C" void kernel_launch(void* const* d_in, const int* in_sizes, int n_in,
                              void* d_out, int out_size, void* d_ws,
                              size_t ws_size, hipStream_t stream) {
  (void)in_sizes; (void)n_in; (void)ws_size;
  const float* h   = (const float*)d_in[0];
  const int*   src = (const int*)d_in[1];
  const int*   dst = (const int*)d_in[2];
  const float* W1f = (const float*)d_in[3];
  const float* b1f = (const float*)d_in[4];
  const float* W2f = (const float*)d_in[5];
  const float* b2f = (const float*)d_in[6];
  const float* W1p = (const float*)d_in[7];
  const float* b1p = (const float*)d_in[8];
  const float* W2p = (const float*)d_in[9];
  const float* b2p = (const float*)d_in[10];

  float* out_adj   = (float*)d_out;
  float* out_hpool = out_adj + (size_t)K_ASSIGN * K_ASSIGN;

  char* ws = (char*)d_ws;
  int* deg_cnt  = (int*)(ws + 0);            //   128,000
  int* rowstart = (int*)(ws + 128000);       //   128,032
  int* cursor   = (int*)(ws + 256032);       //   128,000
  int* bucket   = (int*)(ws + 384032);       // 2,048,000
  unsigned short* h_bf      = (unsigned short*)(ws + 2432032);   // 8,192,000
  unsigned short* x_bf      = (unsigned short*)(ws + 10624032);  // 8,192,000
  unsigned short* feat_bf   = (unsigned short*)(ws + 18816032);  // 8,192,000
  unsigned short* assign_bf = (unsigned short*)(ws + 27008032);  // 6,400,000
  unsigned short* tmp_bf    = (unsigned short*)(ws + 33408032);  // 6,400,000
  unsigned short* w1f_t     = (unsigned short*)(ws + 39808032);  //    32,768
  unsigned short* w2f_t     = (unsigned short*)(ws + 39840800);  //    32,768
  unsigned short* w1p_t     = (unsigned short*)(ws + 39873568);  //   409,600
  unsigned short* w2p_t     = (unsigned short*)(ws + 40283168);  // 5,120,000

  hipMemsetAsync(deg_cnt, 0, 128000, stream);
  hipMemsetAsync(cursor, 0, 128000, stream);
  hipMemsetAsync(d_out, 0, (size_t)out_size * sizeof(float), stream);

  // CSR build (by dst)
  edge_hist<<<N_EDGES / 256, 256, 0, stream>>>(dst, deg_cnt);
  scan_counts<<<1, 256, 0, stream>>>(deg_cnt, rowstart);
  edge_fill<<<N_EDGES / 256, 256, 0, stream>>>(src, dst, rowstart, cursor, bucket);

  // conversions / transposes
  h_to_bf<<<N_NODES * 128 / 4 / 256, 256, 0, stream>>>(h, h_bf);
  transpose_all<<<16 + 16 + 200 + 2500, 256, 0, stream>>>(
      W1f, W2f, W1p, W2p, w1f_t, w2f_t, w1p_t, w2p_t);

  // aggregation (gather) -> x in bf16
  gin_gather<<<N_NODES / 4, 256, 0, stream>>>(rowstart, bucket, h, h_bf, x_bf);

  // feat path: one fused kernel
  feat_fused<<<N_NODES / 128, 512, 0, stream>>>(x_bf, w1f_t, b1f, w2f_t, b2f, feat_bf);

  // assign path: fused 2-layer MFMA + masked softmax, bf16 out (128 rows/blk)
  fused_assign_sm<<<256, 512, 0, stream>>>(x_bf, w1p_t, b1p, w2p_t, b2p, assign_bf);

  // adj @ assign via gather
  tmp_gather<<<N_NODES / 4, 256, 0, stream>>>(rowstart, bucket, assign_bf, tmp_bf);

  // outputs (MFMA)
  pool_adj_mfma<<<NGRAPH * PA_CH * 2, 256, 0, stream>>>(
      assign_bf, feat_bf, tmp_bf, out_adj, out_hpool);
}

// Round 8
// 228.281 us; speedup vs baseline: 10.5131x; 1.0543x over previous
//
#include <hip/hip_runtime.h>

#define N_NODES 32000
#define NPG     2000
#define NGRAPH  16
#define K_ASSIGN 1600
#define KPG     100
#define D_FEAT  128
#define N_EDGES 512000

typedef float f32x4 __attribute__((ext_vector_type(4)));
typedef __bf16 bf16x8 __attribute__((ext_vector_type(8)));

union FragU { unsigned u[4]; bf16x8 v; };

__device__ __forceinline__ float frelu(float v) { return fmaxf(v, 0.0f); }

__device__ __forceinline__ unsigned short f2bf(float f) {
  unsigned u = __float_as_uint(f);
  u += 0x7FFFu + ((u >> 16) & 1u);
  return (unsigned short)(u >> 16);
}
__device__ __forceinline__ float bfLO(unsigned v) { return __uint_as_float(v << 16); }
__device__ __forceinline__ float bfHI(unsigned v) { return __uint_as_float(v & 0xFFFF0000u); }

// ---------------------------------------------------------------------------
// CSR build (scan + fill; histogram lives in prep_all)
// ---------------------------------------------------------------------------
__global__ __launch_bounds__(256) void scan_counts(
    const int* __restrict__ cnt, int* __restrict__ rowstart) {
  __shared__ int sums[256];
  int t = threadIdx.x;
  int base = t * 125;
  int s = 0;
  for (int i = 0; i < 125; i++) s += cnt[base + i];
  sums[t] = s;
  __syncthreads();
  for (int off = 1; off < 256; off <<= 1) {
    int v = (t >= off) ? sums[t - off] : 0;
    __syncthreads();
    sums[t] += v;
    __syncthreads();
  }
  int run = (t == 0) ? 0 : sums[t - 1];
  for (int i = 0; i < 125; i++) {
    rowstart[base + i] = run;
    run += cnt[base + i];
  }
  if (t == 255) rowstart[32000] = run;
}

__global__ __launch_bounds__(256) void edge_fill(
    const int* __restrict__ src, const int* __restrict__ dst,
    const int* __restrict__ rowstart, int* __restrict__ cursor,
    int* __restrict__ bucket) {
  int e = blockIdx.x * 256 + threadIdx.x;
  if (e < N_EDGES) {
    int d = dst[e];
    int pos = atomicAdd(&cursor[d], 1);
    bucket[rowstart[d] + pos] = src[e];
  }
}

// ---------------------------------------------------------------------------
// prep_all: weight transposes (f32->bf16 [C][R]) + h->bf16 + edge histogram,
// fused into one launch (independent works, block-ранges).
// blocks [0,16) W1f, [16,32) W2f, [32,232) W1p, [232,2732) W2p,
// [2732,6732) h_to_bf, [6732,8732) edge_hist.
// ---------------------------------------------------------------------------
__global__ __launch_bounds__(256) void prep_all(
    const float* __restrict__ W1f, const float* __restrict__ W2f,
    const float* __restrict__ W1p, const float* __restrict__ W2p,
    unsigned short* __restrict__ o1, unsigned short* __restrict__ o2,
    unsigned short* __restrict__ o3, unsigned short* __restrict__ o4,
    const float* __restrict__ h, unsigned short* __restrict__ h_bf,
    const int* __restrict__ dst, int* __restrict__ cnt) {
  __shared__ float tile[32][33];
  int b = blockIdx.x;
  int t = threadIdx.x;
  if (b >= 6732) {  // edge histogram
    int e = (b - 6732) * 256 + t;
    if (e < N_EDGES) atomicAdd(&cnt[dst[e]], 1);
    return;
  }
  if (b >= 2732) {  // h -> bf16
    int i = (b - 2732) * 256 + t;  // float4 index
    float4 v = ((const float4*)h)[i];
    ushort4 o;
    o.x = f2bf(v.x); o.y = f2bf(v.y); o.z = f2bf(v.z); o.w = f2bf(v.w);
    ((ushort4*)h_bf)[i] = o;
    return;
  }
  const float* in;
  unsigned short* out;
  int R, C, rb;
  if (b < 16)       { in = W1f; out = o1; R = 128;  C = 128;  rb = b; }
  else if (b < 32)  { in = W2f; out = o2; R = 128;  C = 128;  rb = b - 16; }
  else if (b < 232) { in = W1p; out = o3; R = 128;  C = 1600; rb = b - 32; }
  else              { in = W2p; out = o4; R = 1600; C = 1600; rb = b - 232; }
  int ct = C >> 5;
  int bc = rb % ct, br = rb / ct;
  int r0 = br * 32, c0 = bc * 32;
#pragma unroll
  for (int i = 0; i < 4; i++) {
    int r = (t >> 5) + i * 8, c = t & 31;
    tile[r][c] = in[(size_t)(r0 + r) * C + c0 + c];
  }
  __syncthreads();
#pragma unroll
  for (int i = 0; i < 4; i++) {
    int c = (t >> 5) + i * 8, r = t & 31;
    out[(size_t)(c0 + c) * R + r0 + r] = f2bf(tile[r][c]);
  }
}

// ---------------------------------------------------------------------------
// Gather aggregation + compute_x: x_bf[n] = bf16(h_bf[n] + mean h_bf[src]).
// XCD-chunked block swizzle: each XCD owns 2 graphs -> h_bf slice (1 MB)
// stays resident in that XCD's 4 MB L2 (grid 8000, 8000%8==0, bijective).
// ---------------------------------------------------------------------------
__global__ __launch_bounds__(256) void gin_gather(
    const int* __restrict__ rowstart, const int* __restrict__ bucket,
    const unsigned short* __restrict__ h_bf, unsigned short* __restrict__ x_bf) {
  int bid = (int)(blockIdx.x & 7) * 1000 + (int)(blockIdx.x >> 3);
  int n = bid * 4 + (threadIdx.x >> 6);
  int lane = threadIdx.x & 63;
  int rs = rowstart[n], re = rowstart[n + 1];
  const unsigned* hb = (const unsigned*)h_bf;
  float ax = 0.f, ay = 0.f;
  int e = rs;
  for (; e + 4 <= re; e += 4) {
    unsigned v0 = hb[(size_t)bucket[e] * 64 + lane];
    unsigned v1 = hb[(size_t)bucket[e + 1] * 64 + lane];
    unsigned v2 = hb[(size_t)bucket[e + 2] * 64 + lane];
    unsigned v3 = hb[(size_t)bucket[e + 3] * 64 + lane];
    ax += (bfLO(v0) + bfLO(v1)) + (bfLO(v2) + bfLO(v3));
    ay += (bfHI(v0) + bfHI(v1)) + (bfHI(v2) + bfHI(v3));
  }
  for (; e < re; e++) {
    unsigned v = hb[(size_t)bucket[e] * 64 + lane];
    ax += bfLO(v);
    ay += bfHI(v);
  }
  float invd = 1.0f / fmaxf((float)(re - rs), 1.0f);
  unsigned hv = hb[(size_t)n * 64 + lane];
  unsigned o = ((unsigned)f2bf(bfHI(hv) + ay * invd) << 16) |
               f2bf(bfLO(hv) + ax * invd);
  ((unsigned*)x_bf)[(size_t)n * 64 + lane] = o;
}

// ---------------------------------------------------------------------------
// Fused feat path: feat = relu(relu(x@W1f+b1f)@W2f+b2f), bf16 out.
// ---------------------------------------------------------------------------
#define FF_STR 136
__global__ __launch_bounds__(512) void feat_fused(
    const unsigned short* __restrict__ x_bf,
    const unsigned short* __restrict__ w1t, const float* __restrict__ b1f,
    const unsigned short* __restrict__ w2t, const float* __restrict__ b2f,
    unsigned short* __restrict__ feat_bf) {
  __shared__ __align__(16) unsigned char smem[2 * 34816];
  unsigned short* xa = (unsigned short*)smem;            // xt, then x1
  unsigned short* ws = (unsigned short*)(smem + 34816);  // W1, then W2
  int t = threadIdx.x;
  size_t base = (size_t)blockIdx.x * 128;

#pragma unroll
  for (int i = 0; i < 4; i++) {
    int fi = t + 512 * i;
    int r = fi >> 4, u8 = (fi & 15) * 8;
    *(uint4*)&xa[r * FF_STR + u8] = *(const uint4*)(x_bf + (base + r) * 128 + u8);
    *(uint4*)&ws[r * FF_STR + u8] = *(const uint4*)(w1t + (size_t)r * 128 + u8);
  }
  __syncthreads();

  int w = t >> 6, l = t & 63, lr = l & 15, lg = l >> 4;
  int myrow = 16 * w + lr;
  bf16x8 af[4];
#pragma unroll
  for (int kc = 0; kc < 4; kc++)
    af[kc] = *(bf16x8*)&xa[myrow * FF_STR + 32 * kc + 8 * lg];

  // phase 1: x1^T fragments (swapped)
  f32x4 p[8];
#pragma unroll
  for (int ntk = 0; ntk < 8; ntk++) {
    p[ntk] = (f32x4){0.f, 0.f, 0.f, 0.f};
    int c = 16 * ntk + lr;
#pragma unroll
    for (int kc = 0; kc < 4; kc++) {
      bf16x8 wf = *(bf16x8*)&ws[c * FF_STR + 32 * kc + 8 * lg];
      p[ntk] = __builtin_amdgcn_mfma_f32_16x16x32_bf16(wf, af[kc], p[ntk], 0, 0, 0);
    }
  }
  __syncthreads();  // xt + W1 fully read

  // write x1 (bf16) over xt; stage W2 over W1
#pragma unroll
  for (int ntk = 0; ntk < 8; ntk++) {
    int kk0 = 16 * ntk + 4 * lg;
    float4 b1 = *(const float4*)(b1f + kk0);
    ushort4 pk;
    pk.x = f2bf(frelu(p[ntk][0] + b1.x));
    pk.y = f2bf(frelu(p[ntk][1] + b1.y));
    pk.z = f2bf(frelu(p[ntk][2] + b1.z));
    pk.w = f2bf(frelu(p[ntk][3] + b1.w));
    *(ushort4*)&xa[myrow * FF_STR + kk0] = pk;
  }
#pragma unroll
  for (int i = 0; i < 4; i++) {
    int fi = t + 512 * i;
    int r = fi >> 4, u8 = (fi & 15) * 8;
    *(uint4*)&ws[r * FF_STR + u8] = *(const uint4*)(w2t + (size_t)r * 128 + u8);
  }
  __syncthreads();

  // phase 2 (swapped): feat
  bf16x8 a2[4];
#pragma unroll
  for (int kc = 0; kc < 4; kc++)
    a2[kc] = *(bf16x8*)&xa[myrow * FF_STR + 32 * kc + 8 * lg];
#pragma unroll
  for (int nt = 0; nt < 8; nt++) {
    f32x4 q = (f32x4){0.f, 0.f, 0.f, 0.f};
    int c = 16 * nt + lr;
#pragma unroll
    for (int kc = 0; kc < 4; kc++) {
      bf16x8 wf = *(bf16x8*)&ws[c * FF_STR + 32 * kc + 8 * lg];
      q = __builtin_amdgcn_mfma_f32_16x16x32_bf16(wf, a2[kc], q, 0, 0, 0);
    }
    int c0 = 16 * nt + 4 * lg;
    float4 b2 = *(const float4*)(b2f + c0);
    ushort4 pk;
    pk.x = f2bf(frelu(q[0] + b2.x));
    pk.y = f2bf(frelu(q[1] + b2.y));
    pk.z = f2bf(frelu(q[2] + b2.z));
    pk.w = f2bf(frelu(q[3] + b2.w));
    *(ushort4*)&feat_bf[(base + myrow) * 128 + c0] = pk;
  }
}

// ---------------------------------------------------------------------------
// Fused assign path + softmax. 128 rows/block (256 blocks), 8 waves.
// Wave (rh,h): rows 32rh..+31 (rh 0..3), kk-half 32h..+31 (h 0..1).
// s_setprio(1) around MFMA clusters (T5: phase-split wave roles exist).
// ---------------------------------------------------------------------------
#define FA_WS 136  // 128+8 ushorts (pad rotates banks)
#define FA_PS 72   // 64+8 ushorts
#define FA_W1OFF 17408
#define FA_W2BASE 34816
#define FA_W2OFF 16128
__global__ __launch_bounds__(512) void fused_assign_sm(
    const unsigned short* __restrict__ x_bf, const unsigned short* __restrict__ w1t,
    const float* __restrict__ b1p, const unsigned short* __restrict__ w2t,
    const float* __restrict__ b2p, unsigned short* __restrict__ assign_bf) {
  // [0,34816) xt (128x136) overlaying w1 buf0+buf1;
  // [34816,50944) w2 buf0; [50944,67072) w2 buf1.
  // End reduction reuses [0, 57344).
  __shared__ __align__(16) unsigned char smem[67072];
  unsigned short* xt = (unsigned short*)smem;

  int t = threadIdx.x;
  int g = blockIdx.x >> 4;
  int row0 = (blockIdx.x & 15) << 7;
  int n0 = g * NPG + row0;

  // stage x tile (rows 0..127), zero-fill past NPG
#pragma unroll
  for (int i = 0; i < 4; i++) {
    int fi = t + 512 * i;
    int r = fi >> 4, u8 = (fi & 15) * 8;
    uint4 v = make_uint4(0, 0, 0, 0);
    if (row0 + r < NPG) v = *(const uint4*)(x_bf + (size_t)(n0 + r) * 128 + u8);
    *(uint4*)&xt[r * FA_WS + u8] = v;
  }
  __syncthreads();

  int w = t >> 6, l = t & 63, lr = l & 15, lg = l >> 4;
  int rh = w >> 1, h = w & 1;

  // resident x fragments: rows 32rh+16ct+lr, k = 32kc+8lg..+7
  bf16x8 af[2][4];
#pragma unroll
  for (int ct = 0; ct < 2; ct++)
#pragma unroll
    for (int kc = 0; kc < 4; kc++)
      af[ct][kc] =
          *(bf16x8*)&xt[(32 * rh + 16 * ct + lr) * FA_WS + 32 * kc + 8 * lg];
  __syncthreads();  // xt region becomes w1 buffers

  // stage chunk 0
  {
    unsigned short* w1s = (unsigned short*)smem;
    unsigned short* w2s = (unsigned short*)(smem + FA_W2BASE);
#pragma unroll
    for (int i = 0; i < 2; i++) {
      int fi = t + 512 * i;
      int c = fi >> 4, u8 = (fi & 15) * 8;
      *(uint4*)&w1s[c * FA_WS + u8] = *(const uint4*)(w1t + (size_t)c * 128 + u8);
    }
#pragma unroll
    for (int i = 0; i < 2; i++) {
      int fi = t + 512 * i;
      if (fi < 896) {
        int c = fi >> 3, u8 = (fi & 7) * 8;
        uint4 v = make_uint4(0, 0, 0, 0);
        if (c < KPG)
          v = *(const uint4*)(w2t + (size_t)(g * KPG + c) * K_ASSIGN + u8);
        *(uint4*)&w2s[c * FA_PS + u8] = v;
      }
    }
  }
  __syncthreads();

  f32x4 acc[7][2];
#pragma unroll
  for (int i = 0; i < 7; i++) {
    acc[i][0] = (f32x4){0.f, 0.f, 0.f, 0.f};
    acc[i][1] = (f32x4){0.f, 0.f, 0.f, 0.f};
  }

  for (int cch = 0; cch < 25; cch++) {
    int cur = cch & 1;
    int k0 = cch * 64;
    const unsigned short* w1c = (const unsigned short*)(smem + cur * FA_W1OFF);
    const unsigned short* w2c =
        (const unsigned short*)(smem + FA_W2BASE + cur * FA_W2OFF);
    bool pf = (cch < 24);
    uint4 rA[2], rB[2];
    if (pf) {  // issue next-chunk loads early (hide under MFMA phases)
      int k1 = k0 + 64;
#pragma unroll
      for (int i = 0; i < 2; i++) {
        int fi = t + 512 * i;
        int c = fi >> 4, u8 = (fi & 15) * 8;
        rA[i] = *(const uint4*)(w1t + (size_t)(k1 + c) * 128 + u8);
      }
#pragma unroll
      for (int i = 0; i < 2; i++) {
        int fi = t + 512 * i;
        rB[i] = make_uint4(0, 0, 0, 0);
        if (fi < 896) {
          int c = fi >> 3, u8 = (fi & 7) * 8;
          if (c < KPG)
            rB[i] = *(const uint4*)(w2t + (size_t)(g * KPG + c) * K_ASSIGN +
                                    k1 + u8);
        }
      }
    }

    // phase 1 (swapped): p[nt2][ct] = P^T frag, lane holds
    // P[xrow=32rh+16ct+lr][kk = 16*(2h+nt2) + 4lg + reg]
    f32x4 p[2][2];
    __builtin_amdgcn_s_setprio(1);
#pragma unroll
    for (int nt2 = 0; nt2 < 2; nt2++) {
      p[nt2][0] = (f32x4){0.f, 0.f, 0.f, 0.f};
      p[nt2][1] = (f32x4){0.f, 0.f, 0.f, 0.f};
      int nt = 2 * h + nt2;
#pragma unroll
      for (int kc = 0; kc < 4; kc++) {
        bf16x8 wf = *(bf16x8*)&w1c[(16 * nt + lr) * FA_WS + 32 * kc + 8 * lg];
        p[nt2][0] = __builtin_amdgcn_mfma_f32_16x16x32_bf16(wf, af[0][kc],
                                                            p[nt2][0], 0, 0, 0);
        p[nt2][1] = __builtin_amdgcn_mfma_f32_16x16x32_bf16(wf, af[1][kc],
                                                            p[nt2][1], 0, 0, 0);
      }
    }
    __builtin_amdgcn_s_setprio(0);
    // bias + relu + pack to bf16 pairs
    unsigned q[2][2][2];
#pragma unroll
    for (int nt2 = 0; nt2 < 2; nt2++) {
      int kkb = k0 + 16 * (2 * h + nt2) + 4 * lg;
      float4 b1 = *(const float4*)(b1p + kkb);
#pragma unroll
      for (int ct = 0; ct < 2; ct++) {
        float r0 = frelu(p[nt2][ct][0] + b1.x);
        float r1 = frelu(p[nt2][ct][1] + b1.y);
        float r2 = frelu(p[nt2][ct][2] + b1.z);
        float r3 = frelu(p[nt2][ct][3] + b1.w);
        q[nt2][ct][0] = ((unsigned)f2bf(r1) << 16) | f2bf(r0);
        q[nt2][ct][1] = ((unsigned)f2bf(r3) << 16) | f2bf(r2);
      }
    }
    // regroup to B-frag layout via shfl (within-wave)
    int sA = lr + 32 * (lg & 1);
    int sB = sA + 16;
    bool hi = (lg >= 2);
    FragU pa[2];
#pragma unroll
    for (int ct = 0; ct < 2; ct++) {
      unsigned a0 = (unsigned)__shfl((int)q[0][ct][0], sA, 64);
      unsigned b0 = (unsigned)__shfl((int)q[1][ct][0], sA, 64);
      unsigned a1 = (unsigned)__shfl((int)q[0][ct][1], sA, 64);
      unsigned b1u = (unsigned)__shfl((int)q[1][ct][1], sA, 64);
      unsigned a2 = (unsigned)__shfl((int)q[0][ct][0], sB, 64);
      unsigned b2u = (unsigned)__shfl((int)q[1][ct][0], sB, 64);
      unsigned a3 = (unsigned)__shfl((int)q[0][ct][1], sB, 64);
      unsigned b3u = (unsigned)__shfl((int)q[1][ct][1], sB, 64);
      pa[ct].u[0] = hi ? b0 : a0;
      pa[ct].u[1] = hi ? b1u : a1;
      pa[ct].u[2] = hi ? b2u : a2;
      pa[ct].u[3] = hi ? b3u : a3;
    }
    // phase 2: acc[ct2][ct] += W2^T-frag @ P-frag over klocal 0..31
    __builtin_amdgcn_s_setprio(1);
#pragma unroll
    for (int ct2 = 0; ct2 < 7; ct2++) {
      bf16x8 wv = *(bf16x8*)&w2c[(16 * ct2 + lr) * FA_PS + 32 * h + 8 * lg];
      acc[ct2][0] = __builtin_amdgcn_mfma_f32_16x16x32_bf16(wv, pa[0].v,
                                                            acc[ct2][0], 0, 0, 0);
      acc[ct2][1] = __builtin_amdgcn_mfma_f32_16x16x32_bf16(wv, pa[1].v,
                                                            acc[ct2][1], 0, 0, 0);
    }
    __builtin_amdgcn_s_setprio(0);
    // write prefetched chunk into alternate buffers
    if (pf) {
      unsigned short* w1n = (unsigned short*)(smem + (cur ^ 1) * FA_W1OFF);
      unsigned short* w2n =
          (unsigned short*)(smem + FA_W2BASE + (cur ^ 1) * FA_W2OFF);
#pragma unroll
      for (int i = 0; i < 2; i++) {
        int fi = t + 512 * i;
        int c = fi >> 4, u8 = (fi & 15) * 8;
        *(uint4*)&w1n[c * FA_WS + u8] = rA[i];
      }
#pragma unroll
      for (int i = 0; i < 2; i++) {
        int fi = t + 512 * i;
        if (fi < 896) {
          int c = fi >> 3, u8 = (fi & 7) * 8;
          *(uint4*)&w2n[c * FA_PS + u8] = rB[i];
        }
      }
    }
    __syncthreads();
  }

  // cross-h reduction: h==1 waves dump partials, h==0 waves add
  float* red = (float*)smem;
  if (h == 1) {
#pragma unroll
    for (int ct2 = 0; ct2 < 7; ct2++)
#pragma unroll
      for (int ct = 0; ct < 2; ct++)
        *(f32x4*)&red[((rh * 14 + ct2 * 2 + ct) * 64 + l) * 4] = acc[ct2][ct];
  }
  __syncthreads();
  if (h == 0) {
#pragma unroll
    for (int ct2 = 0; ct2 < 7; ct2++)
#pragma unroll
      for (int ct = 0; ct < 2; ct++)
        acc[ct2][ct] += *(f32x4*)&red[((rh * 14 + ct2 * 2 + ct) * 64 + l) * 4];

    // fused masked softmax; lane holds row 32rh+16ct+lr, cols 16ct2+4lg+r
#pragma unroll
    for (int ct = 0; ct < 2; ct++) {
      int xrow = row0 + 32 * rh + 16 * ct + lr;
      float v[7][4];
      float m = 0.0f;  // reference max includes masked zeros
#pragma unroll
      for (int ct2 = 0; ct2 < 7; ct2++) {
        int col0 = 16 * ct2 + 4 * lg;
        if (col0 < KPG) {
          float4 b2 = *(const float4*)(b2p + g * KPG + col0);
          v[ct2][0] = frelu(acc[ct2][ct][0] + b2.x);
          v[ct2][1] = frelu(acc[ct2][ct][1] + b2.y);
          v[ct2][2] = frelu(acc[ct2][ct][2] + b2.z);
          v[ct2][3] = frelu(acc[ct2][ct][3] + b2.w);
          m = fmaxf(m, fmaxf(fmaxf(v[ct2][0], v[ct2][1]),
                             fmaxf(v[ct2][2], v[ct2][3])));
        }
      }
      m = fmaxf(m, __shfl_xor(m, 16, 64));
      m = fmaxf(m, __shfl_xor(m, 32, 64));
      float s = 0.0f;
#pragma unroll
      for (int ct2 = 0; ct2 < 7; ct2++) {
        int col0 = 16 * ct2 + 4 * lg;
        if (col0 < KPG) {
          v[ct2][0] = expf(v[ct2][0] - m);
          v[ct2][1] = expf(v[ct2][1] - m);
          v[ct2][2] = expf(v[ct2][2] - m);
          v[ct2][3] = expf(v[ct2][3] - m);
          s += (v[ct2][0] + v[ct2][1]) + (v[ct2][2] + v[ct2][3]);
        }
      }
      s += __shfl_xor(s, 16, 64);
      s += __shfl_xor(s, 32, 64);
      float denom = s + (float)(K_ASSIGN - KPG) * expf(-m);
      float scale = 1.0f / (s + 1e-13f * denom);
      if (xrow < NPG) {
#pragma unroll
        for (int ct2 = 0; ct2 < 7; ct2++) {
          int col0 = 16 * ct2 + 4 * lg;
          if (col0 < KPG) {
            ushort4 pk;
            pk.x = f2bf(v[ct2][0] * scale);
            pk.y = f2bf(v[ct2][1] * scale);
            pk.z = f2bf(v[ct2][2] * scale);
            pk.w = f2bf(v[ct2][3] * scale);
            *(ushort4*)(assign_bf + ((size_t)g * NPG + xrow) * KPG + col0) = pk;
          }
        }
      }
    }
  }
}

// ---------------------------------------------------------------------------
// tmp_bf[n] = sum_{e->n} assign_bf[src_e] (100-wide). One wave/node, 50 lanes.
// XCD-chunked swizzle: assign_bf slice of 2 graphs (0.8 MB) L2-resident.
// ---------------------------------------------------------------------------
__global__ __launch_bounds__(256) void tmp_gather(
    const int* __restrict__ rowstart, const int* __restrict__ bucket,
    const unsigned short* __restrict__ assign_bf, unsigned short* __restrict__ tmp_bf) {
  int bid = (int)(blockIdx.x & 7) * 1000 + (int)(blockIdx.x >> 3);
  int n = bid * 4 + (threadIdx.x >> 6);
  int lane = threadIdx.x & 63;
  if (lane >= 50) return;
  int rs = rowstart[n], re = rowstart[n + 1];
  const unsigned* ab = (const unsigned*)assign_bf;
  float ax = 0.f, ay = 0.f;
  int e = rs;
  for (; e + 4 <= re; e += 4) {
    unsigned v0 = ab[(size_t)bucket[e] * 50 + lane];
    unsigned v1 = ab[(size_t)bucket[e + 1] * 50 + lane];
    unsigned v2 = ab[(size_t)bucket[e + 2] * 50 + lane];
    unsigned v3 = ab[(size_t)bucket[e + 3] * 50 + lane];
    ax += (bfLO(v0) + bfLO(v1)) + (bfLO(v2) + bfLO(v3));
    ay += (bfHI(v0) + bfHI(v1)) + (bfHI(v2) + bfHI(v3));
  }
  for (; e < re; e++) {
    unsigned v = ab[(size_t)bucket[e] * 50 + lane];
    ax += bfLO(v);
    ay += bfHI(v);
  }
  unsigned o = ((unsigned)f2bf(ay) << 16) | f2bf(ax);
  ((unsigned*)tmp_bf)[(size_t)n * 50 + lane] = o;
}

// ---------------------------------------------------------------------------
// pool (blocks 0..255) + adj (blocks 256..511), MFMA over K=n.
// ---------------------------------------------------------------------------
#define PA_STR 72
#define PA_CH 16
#define PA_CHN 128
__global__ __launch_bounds__(256) void pool_adj_mfma(
    const unsigned short* __restrict__ assign_bf,
    const unsigned short* __restrict__ feat_bf,
    const unsigned short* __restrict__ tmp_bf,
    float* __restrict__ out_adj, float* __restrict__ out_hpool) {
  __shared__ __align__(16) unsigned short as[112 * PA_STR];  // 16128 B
  __shared__ __align__(16) unsigned short bs[128 * PA_STR];  // 18432 B
  bool is_pool = blockIdx.x < NGRAPH * PA_CH;
  int bb = is_pool ? blockIdx.x : blockIdx.x - NGRAPH * PA_CH;
  int g = bb >> 4, ch = bb & 15;
  int nbase = ch * PA_CHN;
  int lim = NPG - nbase;
  if (lim > PA_CHN) lim = PA_CHN;  // 128, except last chunk: 80
  int t = threadIdx.x;
  int w = t >> 6, l = t & 63, lr = l & 15, lg = l >> 4;
  const unsigned* au = (const unsigned*)assign_bf;
  const unsigned* fu = (const unsigned*)feat_bf;
  const unsigned* tu = (const unsigned*)tmp_bf;

  // zero pad rows (m >= 100 for as; col-rows >= 100 for bs in adj path)
  for (int i = t; i < 12 * PA_STR; i += 256) as[100 * PA_STR + i] = 0;
  for (int i = t; i < 28 * PA_STR; i += 256) bs[100 * PA_STR + i] = 0;

  f32x4 acc[7][2];
#pragma unroll
  for (int i = 0; i < 7; i++) {
    acc[i][0] = (f32x4){0.f, 0.f, 0.f, 0.f};
    acc[i][1] = (f32x4){0.f, 0.f, 0.f, 0.f};
  }

  for (int kt = 0; kt < 2; kt++) {
    int nt0 = kt * 64;
    __syncthreads();  // prev compute done (and initial zero visible)
    // stage A (transpose): 64 n x 50 k-pairs from assign
#pragma unroll
    for (int i = 0; i < 13; i++) {
      int idx = t + 256 * i;
      if (idx < 3200) {
        int r = idx / 50, cu = idx % 50;
        int nl = nt0 + r;
        unsigned v = 0;
        if (nl < lim) v = au[(size_t)(g * NPG + nbase + nl) * 50 + cu];
        as[(2 * cu) * PA_STR + r] = (unsigned short)(v & 0xFFFFu);
        as[(2 * cu + 1) * PA_STR + r] = (unsigned short)(v >> 16);
      }
    }
    if (is_pool) {  // stage B = feat (64 n x 64 d-pairs)
#pragma unroll
      for (int i = 0; i < 16; i++) {
        int idx = t + 256 * i;
        int r = idx >> 6, cu = idx & 63;
        int nl = nt0 + r;
        unsigned v = 0;
        if (nl < lim) v = fu[(size_t)(g * NPG + nbase + nl) * 64 + cu];
        bs[(2 * cu) * PA_STR + r] = (unsigned short)(v & 0xFFFFu);
        bs[(2 * cu + 1) * PA_STR + r] = (unsigned short)(v >> 16);
      }
    } else {  // stage B = tmp (64 n x 50 k2-pairs)
#pragma unroll
      for (int i = 0; i < 13; i++) {
        int idx = t + 256 * i;
        if (idx < 3200) {
          int r = idx / 50, cu = idx % 50;
          int nl = nt0 + r;
          unsigned v = 0;
          if (nl < lim) v = tu[(size_t)(g * NPG + nbase + nl) * 50 + cu];
          bs[(2 * cu) * PA_STR + r] = (unsigned short)(v & 0xFFFFu);
          bs[(2 * cu + 1) * PA_STR + r] = (unsigned short)(v >> 16);
        }
      }
    }
    __syncthreads();
    // compute: 2 MFMA-K steps of 32 over the 64-n tile
#pragma unroll
    for (int kc = 0; kc < 2; kc++) {
      bf16x8 afr[7];
#pragma unroll
      for (int mt = 0; mt < 7; mt++)
        afr[mt] = *(bf16x8*)&as[(16 * mt + lr) * PA_STR + 32 * kc + 8 * lg];
#pragma unroll
      for (int nt2 = 0; nt2 < 2; nt2++) {
        int nt = 2 * w + nt2;
        bf16x8 bfr = *(bf16x8*)&bs[(16 * nt + lr) * PA_STR + 32 * kc + 8 * lg];
#pragma unroll
        for (int mt = 0; mt < 7; mt++)
          acc[mt][nt2] =
              __builtin_amdgcn_mfma_f32_16x16x32_bf16(afr[mt], bfr, acc[mt][nt2], 0, 0, 0);
      }
    }
  }

  // epilogue: atomic f32 adds; D[row = 16mt+4lg+r][col = 16nt+lr]
  if (is_pool) {
#pragma unroll
    for (int mt = 0; mt < 7; mt++)
#pragma unroll
      for (int nt2 = 0; nt2 < 2; nt2++) {
        int nt = 2 * w + nt2;
#pragma unroll
        for (int r = 0; r < 4; r++) {
          int m = 16 * mt + 4 * lg + r;
          if (m < KPG)
            atomicAdd(out_hpool + ((size_t)g * KPG + m) * 128 + 16 * nt + lr,
                      acc[mt][nt2][r]);
        }
      }
  } else {
#pragma unroll
    for (int mt = 0; mt < 7; mt++)
#pragma unroll
      for (int nt2 = 0; nt2 < 2; nt2++) {
        int nt = 2 * w + nt2;
        if (nt < 7) {
          int k2 = 16 * nt + lr;
          if (k2 < KPG) {
#pragma unroll
            for (int r = 0; r < 4; r++) {
              int m = 16 * mt + 4 * lg + r;
              if (m < KPG)
                atomicAdd(out_adj + ((size_t)g * KPG + m) * K_ASSIGN + g * KPG + k2,
                          acc[mt][nt2][r]);
            }
          }
        }
      }
  }
}

extern "C" void kernel_launch(void* const* d_in, const int* in_sizes, int n_in,
                              void* d_out, int out_size, void* d_ws,
                              size_t ws_size, hipStream_t stream) {
  (void)in_sizes; (void)n_in; (void)ws_size;
  const float* h   = (const float*)d_in[0];
  const int*   src = (const int*)d_in[1];
  const int*   dst = (const int*)d_in[2];
  const float* W1f = (const float*)d_in[3];
  const float* b1f = (const float*)d_in[4];
  const float* W2f = (const float*)d_in[5];
  const float* b2f = (const float*)d_in[6];
  const float* W1p = (const float*)d_in[7];
  const float* b1p = (const float*)d_in[8];
  const float* W2p = (const float*)d_in[9];
  const float* b2p = (const float*)d_in[10];

  float* out_adj   = (float*)d_out;
  float* out_hpool = out_adj + (size_t)K_ASSIGN * K_ASSIGN;

  char* ws = (char*)d_ws;
  int* deg_cnt  = (int*)(ws + 0);            //   128,000
  int* rowstart = (int*)(ws + 128000);       //   128,032
  int* cursor   = (int*)(ws + 256032);       //   128,000
  int* bucket   = (int*)(ws + 384032);       // 2,048,000
  unsigned short* h_bf      = (unsigned short*)(ws + 2432032);   // 8,192,000
  unsigned short* x_bf      = (unsigned short*)(ws + 10624032);  // 8,192,000
  unsigned short* feat_bf   = (unsigned short*)(ws + 18816032);  // 8,192,000
  unsigned short* assign_bf = (unsigned short*)(ws + 27008032);  // 6,400,000
  unsigned short* tmp_bf    = (unsigned short*)(ws + 33408032);  // 6,400,000
  unsigned short* w1f_t     = (unsigned short*)(ws + 39808032);  //    32,768
  unsigned short* w2f_t     = (unsigned short*)(ws + 39840800);  //    32,768
  unsigned short* w1p_t     = (unsigned short*)(ws + 39873568);  //   409,600
  unsigned short* w2p_t     = (unsigned short*)(ws + 40283168);  // 5,120,000

  hipMemsetAsync(deg_cnt, 0, 128000, stream);
  hipMemsetAsync(cursor, 0, 128000, stream);
  hipMemsetAsync(d_out, 0, (size_t)out_size * sizeof(float), stream);

  // transposes + h->bf16 + edge histogram, one launch
  prep_all<<<8732, 256, 0, stream>>>(W1f, W2f, W1p, W2p, w1f_t, w2f_t, w1p_t,
                                     w2p_t, h, h_bf, dst, deg_cnt);

  // CSR build (by dst)
  scan_counts<<<1, 256, 0, stream>>>(deg_cnt, rowstart);
  edge_fill<<<N_EDGES / 256, 256, 0, stream>>>(src, dst, rowstart, cursor, bucket);

  // aggregation (gather, XCD-swizzled) -> x in bf16
  gin_gather<<<N_NODES / 4, 256, 0, stream>>>(rowstart, bucket, h_bf, x_bf);

  // feat path: one fused kernel
  feat_fused<<<N_NODES / 128, 512, 0, stream>>>(x_bf, w1f_t, b1f, w2f_t, b2f, feat_bf);

  // assign path: fused 2-layer MFMA + masked softmax, bf16 out (128 rows/blk)
  fused_assign_sm<<<256, 512, 0, stream>>>(x_bf, w1p_t, b1p, w2p_t, b2p, assign_bf);

  // adj @ assign via gather (XCD-swizzled)
  tmp_gather<<<N_NODES / 4, 256, 0, stream>>>(rowstart, bucket, assign_bf, tmp_bf);

  // outputs (MFMA)
  pool_adj_mfma<<<NGRAPH * PA_CH * 2, 256, 0, stream>>>(
      assign_bf, feat_bf, tmp_bf, out_adj, out_hpool);
}